// Round 13
// baseline (243.700 us; speedup 1.0000x reference)
//
#include <hip/hip_runtime.h>
#include <hip/hip_bf16.h>
#include <math.h>

#define FEAT 64
#define NB_PAD 512          // padded bucket count (nodes/bucket = 256)
#define PART_GRID 1024      // hist/partition grid (4 blocks/CU)
#define SRC_BITS 17         // N <= 131072

typedef __attribute__((ext_vector_type(8))) short short8;   // 8 bf16 (4 VGPRs)
typedef __attribute__((ext_vector_type(4))) float f32x4;    // MFMA C/D

// ---- bf16 helpers (RNE pack, exact unpack) --------------------------------
__device__ __forceinline__ float bf_lo(unsigned u) { return __uint_as_float(u << 16); }
__device__ __forceinline__ float bf_hi(unsigned u) { return __uint_as_float(u & 0xFFFF0000u); }
__device__ __forceinline__ unsigned short f2bf(float f) {
    unsigned b = __float_as_uint(f);
    return (unsigned short)((b + 0x7FFFu + ((b >> 16) & 1u)) >> 16);
}
__device__ __forceinline__ unsigned pack_exact(float lo, float hi) {
    return (__float_as_uint(lo) >> 16) | (__float_as_uint(hi) & 0xFFFF0000u);
}

// ---------------------------------------------------------------------------
__global__ void zero_kernel(int* __restrict__ p, int n) {
    int i = blockIdx.x * blockDim.x + threadIdx.x;
    if (i < n) p[i] = 0;
}

// ---------------------------------------------------------------------------
// Stage 1: global bucket histogram (bucket = dst >> 8), per-block LDS hist.
// ---------------------------------------------------------------------------
__global__ __launch_bounds__(256) void hist_kernel(const int* __restrict__ dst,
                                                   int* __restrict__ bktCnt, int nE) {
    __shared__ int hist[NB_PAD];
    int t = threadIdx.x;
    hist[t] = 0; hist[t + 256] = 0;
    __syncthreads();
    int chunk = ((nE + PART_GRID - 1) / PART_GRID + 1) & ~1;   // even
    int begin = blockIdx.x * chunk;
    int end = begin + chunk; if (end > nE) end = nE;
    for (int i = begin + 2 * t; i < end; i += 512) {
        if (i + 1 < end) {
            int2 d2 = *(const int2*)&dst[i];
            atomicAdd(&hist[d2.x >> 8], 1);
            atomicAdd(&hist[d2.y >> 8], 1);
        } else {
            atomicAdd(&hist[dst[i] >> 8], 1);
        }
    }
    __syncthreads();
    if (hist[t])       atomicAdd(&bktCnt[t], hist[t]);
    if (hist[t + 256]) atomicAdd(&bktCnt[t + 256], hist[t + 256]);
}

// ---------------------------------------------------------------------------
// Stage 2: exclusive scan of NB_PAD bucket counts -> bktBase, init bktCursor.
// ---------------------------------------------------------------------------
__global__ void bucket_scan_kernel(const int* __restrict__ bktCnt,
                                   int* __restrict__ bktBase,
                                   int* __restrict__ bktCursor) {
    __shared__ int wsum[4];
    int t = threadIdx.x;
    int d0 = bktCnt[2 * t], d1 = bktCnt[2 * t + 1];
    int ps = d0 + d1;
    int lane = t & 63, w = t >> 6;
    int inc = ps;
    for (int d = 1; d < 64; d <<= 1) { int tt = __shfl_up(inc, d); if (lane >= d) inc += tt; }
    if (lane == 63) wsum[w] = inc;
    __syncthreads();
    if (t == 0) { int r = 0; for (int k = 0; k < 4; ++k) { int v = wsum[k]; wsum[k] = r; r += v; } }
    __syncthreads();
    int pexc = (inc - ps) + wsum[w];
    bktBase[2 * t] = pexc;        bktCursor[2 * t] = pexc;
    bktBase[2 * t + 1] = pexc + d0; bktCursor[2 * t + 1] = pexc + d0;
}

// ---------------------------------------------------------------------------
// Stage 3: partition edges into per-bucket packed arrays:
// pk = (dstLocal << SRC_BITS) | src. LDS hist -> one global reservation per
// (block,bucket) -> LDS-rank writes. Hot atomics all LDS.
// ---------------------------------------------------------------------------
__global__ __launch_bounds__(256) void partition_kernel(const int* __restrict__ src,
                                                        const int* __restrict__ dst,
                                                        int* __restrict__ bktCursor,
                                                        unsigned* __restrict__ pairs, int nE) {
    __shared__ int hist[NB_PAD];
    __shared__ int lofs[NB_PAD];
    int t = threadIdx.x;
    hist[t] = 0; hist[t + 256] = 0;
    __syncthreads();
    int chunk = ((nE + PART_GRID - 1) / PART_GRID + 1) & ~1;
    int begin = blockIdx.x * chunk;
    int end = begin + chunk; if (end > nE) end = nE;
    for (int i = begin + 2 * t; i < end; i += 512) {
        if (i + 1 < end) {
            int2 d2 = *(const int2*)&dst[i];
            atomicAdd(&hist[d2.x >> 8], 1);
            atomicAdd(&hist[d2.y >> 8], 1);
        } else {
            atomicAdd(&hist[dst[i] >> 8], 1);
        }
    }
    __syncthreads();
    int c0 = hist[t], c1 = hist[t + 256];
    lofs[t]       = c0 ? atomicAdd(&bktCursor[t], c0) : 0;
    lofs[t + 256] = c1 ? atomicAdd(&bktCursor[t + 256], c1) : 0;
    __syncthreads();
    for (int i = begin + 2 * t; i < end; i += 512) {
        if (i + 1 < end) {
            int2 d2 = *(const int2*)&dst[i];
            int2 s2 = *(const int2*)&src[i];
            int p0 = atomicAdd(&lofs[d2.x >> 8], 1);
            pairs[p0] = ((unsigned)(d2.x & 255) << SRC_BITS) | (unsigned)s2.x;
            int p1 = atomicAdd(&lofs[d2.y >> 8], 1);
            pairs[p1] = ((unsigned)(d2.y & 255) << SRC_BITS) | (unsigned)s2.y;
        } else {
            int d = dst[i];
            int pos = atomicAdd(&lofs[d >> 8], 1);
            pairs[pos] = ((unsigned)(d & 255) << SRC_BITS) | (unsigned)src[i];
        }
    }
}

// ---------------------------------------------------------------------------
// Stage 4: per-bucket CSR finalize (packed pairs).
// ---------------------------------------------------------------------------
__global__ __launch_bounds__(256) void csr_bucket_kernel(const unsigned* __restrict__ pairs,
                                                         const int* __restrict__ bktBase,
                                                         int* __restrict__ off,
                                                         int* __restrict__ csr,
                                                         int N, int E) {
    __shared__ int deg[256];
    __shared__ int cur[256];
    __shared__ int wsum[4];
    int b = blockIdx.x;
    int t = threadIdx.x;
    int lo = b << 8;
    int nloc = N - lo; if (nloc > 256) nloc = 256;
    int e0 = bktBase[b], e1 = bktBase[b + 1];
    deg[t] = 0;
    __syncthreads();
    for (int e = e0 + t; e < e1; e += 256)
        atomicAdd(&deg[pairs[e] >> SRC_BITS], 1);
    __syncthreads();
    int v = deg[t];
    int lane = t & 63, w = t >> 6;
    int inc = v;
    for (int d = 1; d < 64; d <<= 1) { int tt = __shfl_up(inc, d); if (lane >= d) inc += tt; }
    if (lane == 63) wsum[w] = inc;
    __syncthreads();
    if (t == 0) { int r = 0; for (int k = 0; k < 4; ++k) { int x = wsum[k]; wsum[k] = r; r += x; } }
    __syncthreads();
    int excl = (inc - v) + wsum[w];
    if (t < nloc) off[lo + t] = e0 + excl;
    cur[t] = excl;
    if (b == 0 && t == 0) off[N] = E;
    __syncthreads();
    for (int e = e0 + t; e < e1; e += 256) {
        unsigned p = pairs[e];
        int pos = atomicAdd(&cur[p >> SRC_BITS], 1);
        csr[e0 + pos] = (int)(p & ((1u << SRC_BITS) - 1));
    }
}

// ---------------------------------------------------------------------------
// prep: Wl -> bf16, (Wr+Ws) -> bf16, bias = bl+bs (f32)
// ---------------------------------------------------------------------------
__global__ void prep_kernel(const float* __restrict__ Wl0, const float* __restrict__ Wr0,
                            const float* __restrict__ Ws0, const float* __restrict__ bl0,
                            const float* __restrict__ bs0,
                            const float* __restrict__ Wl1, const float* __restrict__ Wr1,
                            const float* __restrict__ Ws1, const float* __restrict__ bl1,
                            const float* __restrict__ bs1,
                            const float* __restrict__ Wl2, const float* __restrict__ Wr2,
                            const float* __restrict__ Ws2, const float* __restrict__ bl2,
                            const float* __restrict__ bs2,
                            unsigned short* __restrict__ wlb,
                            unsigned short* __restrict__ wcb,
                            float* __restrict__ bias) {
    int i = blockIdx.x * blockDim.x + threadIdx.x;
    if (i < 3 * FEAT * FEAT) {
        int li = i >> 12, j = i & 4095;
        const float* Wl = (li == 0) ? Wl0 : (li == 1) ? Wl1 : Wl2;
        const float* Wr = (li == 0) ? Wr0 : (li == 1) ? Wr1 : Wr2;
        const float* Ws = (li == 0) ? Ws0 : (li == 1) ? Ws1 : Ws2;
        wlb[i] = f2bf(Wl[j]);
        wcb[i] = f2bf(Wr[j] + Ws[j]);
    }
    if (i < 3 * FEAT) {
        int li = i >> 6, j = i & 63;
        const float* bl = (li == 0) ? bl0 : (li == 1) ? bl1 : bl2;
        const float* bs = (li == 0) ? bs0 : (li == 1) ? bs1 : bs2;
        bias[i] = bl[j] + bs[j];
    }
}

// ---------------------------------------------------------------------------
// x (f32) -> xb (bf16), 8 elems/thread
// ---------------------------------------------------------------------------
__global__ __launch_bounds__(256) void conv_kernel(const float* __restrict__ in,
                                                   unsigned short* __restrict__ outb,
                                                   int nElem) {
    int base = (blockIdx.x * blockDim.x + threadIdx.x) * 8;
    if (base >= nElem) return;
    float4 a = *(const float4*)(in + base);
    float4 b = *(const float4*)(in + base + 4);
    ushort4 p0 = {f2bf(a.x), f2bf(a.y), f2bf(a.z), f2bf(a.w)};
    ushort4 p1 = {f2bf(b.x), f2bf(b.y), f2bf(b.z), f2bf(b.w)};
    *(ushort4*)(outb + base) = p0;
    *(ushort4*)(outb + base + 4) = p1;
}

// ---------------------------------------------------------------------------
// Max-aggregation on bf16 rows (128 B/row): 8-lane group per node,
// 8 rows in flight per group.
// ---------------------------------------------------------------------------
__global__ __launch_bounds__(256) void agg_kernel(const unsigned short* __restrict__ hb,
                                                  const int* __restrict__ off,
                                                  const int* __restrict__ csr_src,
                                                  unsigned short* __restrict__ ab,
                                                  int nNodes) {
    int gid = blockIdx.x * blockDim.x + threadIdx.x;
    int n = gid >> 3;
    int q = gid & 7;
    if (n >= nNodes) return;

    int e0 = off[n], e1 = off[n + 1];
    const float NEG = -INFINITY;
    float acc[8] = {NEG, NEG, NEG, NEG, NEG, NEG, NEG, NEG};

#define ACCUM(v)                                            \
        acc[0] = fmaxf(acc[0], bf_lo(v.x)); acc[1] = fmaxf(acc[1], bf_hi(v.x)); \
        acc[2] = fmaxf(acc[2], bf_lo(v.y)); acc[3] = fmaxf(acc[3], bf_hi(v.y)); \
        acc[4] = fmaxf(acc[4], bf_lo(v.z)); acc[5] = fmaxf(acc[5], bf_hi(v.z)); \
        acc[6] = fmaxf(acc[6], bf_lo(v.w)); acc[7] = fmaxf(acc[7], bf_hi(v.w));

    int e = e0;
    for (; e + 8 <= e1; e += 8) {
        int s0 = csr_src[e],     s1 = csr_src[e + 1], s2 = csr_src[e + 2], s3 = csr_src[e + 3];
        int s4 = csr_src[e + 4], s5 = csr_src[e + 5], s6 = csr_src[e + 6], s7 = csr_src[e + 7];
        uint4 v0 = *(const uint4*)&hb[(size_t)s0 * FEAT + q * 8];
        uint4 v1 = *(const uint4*)&hb[(size_t)s1 * FEAT + q * 8];
        uint4 v2 = *(const uint4*)&hb[(size_t)s2 * FEAT + q * 8];
        uint4 v3 = *(const uint4*)&hb[(size_t)s3 * FEAT + q * 8];
        uint4 v4 = *(const uint4*)&hb[(size_t)s4 * FEAT + q * 8];
        uint4 v5 = *(const uint4*)&hb[(size_t)s5 * FEAT + q * 8];
        uint4 v6 = *(const uint4*)&hb[(size_t)s6 * FEAT + q * 8];
        uint4 v7 = *(const uint4*)&hb[(size_t)s7 * FEAT + q * 8];
        ACCUM(v0) ACCUM(v1) ACCUM(v2) ACCUM(v3)
        ACCUM(v4) ACCUM(v5) ACCUM(v6) ACCUM(v7)
    }
    for (; e + 4 <= e1; e += 4) {
        int s0 = csr_src[e], s1 = csr_src[e + 1], s2 = csr_src[e + 2], s3 = csr_src[e + 3];
        uint4 v0 = *(const uint4*)&hb[(size_t)s0 * FEAT + q * 8];
        uint4 v1 = *(const uint4*)&hb[(size_t)s1 * FEAT + q * 8];
        uint4 v2 = *(const uint4*)&hb[(size_t)s2 * FEAT + q * 8];
        uint4 v3 = *(const uint4*)&hb[(size_t)s3 * FEAT + q * 8];
        ACCUM(v0) ACCUM(v1) ACCUM(v2) ACCUM(v3)
    }
    for (; e < e1; ++e) {
        int s0 = csr_src[e];
        uint4 v0 = *(const uint4*)&hb[(size_t)s0 * FEAT + q * 8];
        ACCUM(v0)
    }
#undef ACCUM

    uint4 outv;
    if (e1 > e0) {
        outv.x = pack_exact(acc[0], acc[1]);
        outv.y = pack_exact(acc[2], acc[3]);
        outv.z = pack_exact(acc[4], acc[5]);
        outv.w = pack_exact(acc[6], acc[7]);
    } else {
        outv = make_uint4(0, 0, 0, 0);
    }
    *(uint4*)&ab[(size_t)n * FEAT + q * 8] = outv;
}

// ---------------------------------------------------------------------------
// MFMA transform: out[n][f] = relu(sum_k agg[n][k]*Wl[f][k] + h[n][k]*Wc[f][k]
//                                  + bias[f]). Per 16-node tile: 4x
// mfma_f32_16x16x32_bf16, no LDS. C/D layout (guide m89): n=lane&15,
// f = f0 + (lane>>4)*4 + reg.
// ---------------------------------------------------------------------------
template <bool BF16OUT>
__global__ __launch_bounds__(256) void transform_mfma_kernel(
        const unsigned short* __restrict__ hb,
        const unsigned short* __restrict__ ab,
        const unsigned short* __restrict__ Wlb,
        const unsigned short* __restrict__ Wcb,
        const float* __restrict__ bias,
        float* __restrict__ outf,
        unsigned short* __restrict__ outb,
        int nNodes, int tpb, int nTiles) {
    int wave = threadIdx.x >> 6;
    int lane = threadIdx.x & 63;
    int f0 = wave << 4;
    int lm = lane & 15;
    int lk = lane >> 4;

    short8 aWl0 = *(const short8*)&Wlb[(f0 + lm) * FEAT + lk * 8];
    short8 aWl1 = *(const short8*)&Wlb[(f0 + lm) * FEAT + lk * 8 + 32];
    short8 aWc0 = *(const short8*)&Wcb[(f0 + lm) * FEAT + lk * 8];
    short8 aWc1 = *(const short8*)&Wcb[(f0 + lm) * FEAT + lk * 8 + 32];
    f32x4 b4 = *(const f32x4*)&bias[f0 + lk * 4];

    int t0 = blockIdx.x * tpb;
    int t1 = t0 + tpb; if (t1 > nTiles) t1 = nTiles;
#pragma unroll 2
    for (int t = t0; t < t1; ++t) {
        int nb = t << 4;
        int n = nb + lm;
        int nr = (n < nNodes) ? n : (nNodes - 1);
        const unsigned short* __restrict__ ar = ab + (size_t)nr * FEAT;
        const unsigned short* __restrict__ hr = hb + (size_t)nr * FEAT;
        short8 bA0 = *(const short8*)(ar + lk * 8);
        short8 bA1 = *(const short8*)(ar + lk * 8 + 32);
        short8 bH0 = *(const short8*)(hr + lk * 8);
        short8 bH1 = *(const short8*)(hr + lk * 8 + 32);

        f32x4 acc = {0.f, 0.f, 0.f, 0.f};
        acc = __builtin_amdgcn_mfma_f32_16x16x32_bf16(aWl0, bA0, acc, 0, 0, 0);
        acc = __builtin_amdgcn_mfma_f32_16x16x32_bf16(aWl1, bA1, acc, 0, 0, 0);
        acc = __builtin_amdgcn_mfma_f32_16x16x32_bf16(aWc0, bH0, acc, 0, 0, 0);
        acc = __builtin_amdgcn_mfma_f32_16x16x32_bf16(aWc1, bH1, acc, 0, 0, 0);

        if (n < nNodes) {
            float v0 = fmaxf(acc[0] + b4[0], 0.f);
            float v1 = fmaxf(acc[1] + b4[1], 0.f);
            float v2 = fmaxf(acc[2] + b4[2], 0.f);
            float v3 = fmaxf(acc[3] + b4[3], 0.f);
            if (BF16OUT) {
                ushort4 p = {f2bf(v0), f2bf(v1), f2bf(v2), f2bf(v3)};
                *(ushort4*)&outb[(size_t)n * FEAT + f0 + lk * 4] = p;
            } else {
                float4 p = make_float4(v0, v1, v2, v3);
                *(float4*)&outf[(size_t)n * FEAT + f0 + lk * 4] = p;
            }
        }
    }
}

// ---------------------------------------------------------------------------
extern "C" void kernel_launch(void* const* d_in, const int* in_sizes, int n_in,
                              void* d_out, int out_size, void* d_ws, size_t ws_size,
                              hipStream_t stream) {
    const float* x   = (const float*)d_in[0];
    const int* eidx  = (const int*)d_in[1];
    const int N  = in_sizes[0] / FEAT;
    const int E  = in_sizes[1] / 2;
    const int* src = eidx;
    const int* dst = eidx + E;

    const float* Wl[3]; const float* bl[3]; const float* Wr[3];
    const float* Ws[3]; const float* bs[3];
    for (int li = 0; li < 3; ++li) {
        Wl[li] = (const float*)d_in[2 + 5 * li + 0];
        bl[li] = (const float*)d_in[2 + 5 * li + 1];
        Wr[li] = (const float*)d_in[2 + 5 * li + 2];
        Ws[li] = (const float*)d_in[2 + 5 * li + 3];
        bs[li] = (const float*)d_in[2 + 5 * li + 4];
    }

    auto align256 = [](size_t v) { return (v + 255) & ~(size_t)255; };
    char* ws = (char*)d_ws;
    int* off       = (int*)ws;  ws += align256((size_t)(N + 1) * 4);
    int* bktCnt    = (int*)ws;  ws += align256(NB_PAD * 4);
    int* bktBase   = (int*)ws;  ws += align256((NB_PAD + 1) * 4);
    int* bktCursor = (int*)ws;  ws += align256(NB_PAD * 4);
    unsigned* pairs = (unsigned*)ws; ws += align256((size_t)E * 4);
    int* csr_src   = (int*)ws;  ws += align256((size_t)E * 4);
    unsigned short* wlb = (unsigned short*)ws; ws += align256(3 * FEAT * FEAT * 2);
    unsigned short* wcb = (unsigned short*)ws; ws += align256(3 * FEAT * FEAT * 2);
    float* biasbuf = (float*)ws; ws += align256(3 * FEAT * 4);
    unsigned short* xb  = (unsigned short*)ws; ws += align256((size_t)N * FEAT * 2);
    unsigned short* ab  = (unsigned short*)ws; ws += align256((size_t)N * FEAT * 2);
    unsigned short* h1b = (unsigned short*)ws; ws += align256((size_t)N * FEAT * 2);
    unsigned short* h2b = (unsigned short*)ws; ws += align256((size_t)N * FEAT * 2);

    const int TB = 256;
    int nBkt = (N + 255) >> 8;

    // ---- CSR build: hist -> scan -> partition -> per-bucket finalize ----
    zero_kernel<<<2, TB, 0, stream>>>(bktCnt, NB_PAD);
    hist_kernel<<<PART_GRID, TB, 0, stream>>>(dst, bktCnt, E);
    bucket_scan_kernel<<<1, TB, 0, stream>>>(bktCnt, bktBase, bktCursor);
    partition_kernel<<<PART_GRID, TB, 0, stream>>>(src, dst, bktCursor, pairs, E);
    csr_bucket_kernel<<<nBkt, TB, 0, stream>>>(pairs, bktBase, off, csr_src, N, E);

    prep_kernel<<<(3 * FEAT * FEAT + TB - 1) / TB, TB, 0, stream>>>(
        Wl[0], Wr[0], Ws[0], bl[0], bs[0],
        Wl[1], Wr[1], Ws[1], bl[1], bs[1],
        Wl[2], Wr[2], Ws[2], bl[2], bs[2], wlb, wcb, biasbuf);
    int convBlocks = (N * FEAT / 8 + TB - 1) / TB;
    conv_kernel<<<convBlocks, TB, 0, stream>>>(x, xb, N * FEAT);

    int aggBlocks = (N * 8 + TB - 1) / TB;
    int nTiles16 = (N + 15) / 16;
    const int TPB = 4;
    int trfBlocks = (nTiles16 + TPB - 1) / TPB;

    // ---- layer 0 ----
    agg_kernel<<<aggBlocks, TB, 0, stream>>>(xb, off, csr_src, ab, N);
    transform_mfma_kernel<true><<<trfBlocks, TB, 0, stream>>>(
        xb, ab, wlb + 0 * 4096, wcb + 0 * 4096, biasbuf + 0 * 64, nullptr, h1b, N, TPB, nTiles16);
    // ---- layer 1 ----
    agg_kernel<<<aggBlocks, TB, 0, stream>>>(h1b, off, csr_src, ab, N);
    transform_mfma_kernel<true><<<trfBlocks, TB, 0, stream>>>(
        h1b, ab, wlb + 1 * 4096, wcb + 1 * 4096, biasbuf + 1 * 64, nullptr, h2b, N, TPB, nTiles16);
    // ---- layer 2 (f32 output) ----
    agg_kernel<<<aggBlocks, TB, 0, stream>>>(h2b, off, csr_src, ab, N);
    transform_mfma_kernel<false><<<trfBlocks, TB, 0, stream>>>(
        h2b, ab, wlb + 2 * 4096, wcb + 2 * 4096, biasbuf + 2 * 64, (float*)d_out, nullptr, N, TPB, nTiles16);
}

// Round 14
// 208.782 us; speedup vs baseline: 1.1672x; 1.1672x over previous
//
#include <hip/hip_runtime.h>
#include <hip/hip_bf16.h>
#include <math.h>

#define FEAT 64
#define BKT_SHIFT 9          // 512 nodes per bucket
#define NB_PAD 256           // padded bucket count (ceil(100000/512)=196)
#define PART_GRID 256
#define SRC_BITS 17          // N <= 131072; dstLocal (9b) << 17 fits 26 bits

typedef __attribute__((ext_vector_type(8))) short short8;   // 8 bf16 (4 VGPRs)
typedef __attribute__((ext_vector_type(4))) float f32x4;    // MFMA C/D

// ---- bf16 helpers (RNE pack, exact unpack) --------------------------------
__device__ __forceinline__ float bf_lo(unsigned u) { return __uint_as_float(u << 16); }
__device__ __forceinline__ float bf_hi(unsigned u) { return __uint_as_float(u & 0xFFFF0000u); }
__device__ __forceinline__ unsigned short f2bf(float f) {
    unsigned b = __float_as_uint(f);
    return (unsigned short)((b + 0x7FFFu + ((b >> 16) & 1u)) >> 16);
}
__device__ __forceinline__ unsigned pack_exact(float lo, float hi) {
    return (__float_as_uint(lo) >> 16) | (__float_as_uint(hi) & 0xFFFF0000u);
}

// ---------------------------------------------------------------------------
__global__ void zero_kernel(int* __restrict__ p, int n) {
    int i = blockIdx.x * blockDim.x + threadIdx.x;
    if (i < n) p[i] = 0;
}

// ---------------------------------------------------------------------------
// Stage 1: global bucket histogram (bucket = dst >> BKT_SHIFT), LDS hist.
// ---------------------------------------------------------------------------
__global__ __launch_bounds__(256) void hist_kernel(const int* __restrict__ dst,
                                                   int* __restrict__ bktCnt, int nE) {
    __shared__ int hist[NB_PAD];
    int t = threadIdx.x;
    hist[t] = 0;
    __syncthreads();
    int chunk = ((nE + PART_GRID - 1) / PART_GRID + 1) & ~1;
    int begin = blockIdx.x * chunk;
    int end = begin + chunk; if (end > nE) end = nE;
    for (int i = begin + 2 * t; i < end; i += 512) {
        if (i + 1 < end) {
            int2 d2 = *(const int2*)&dst[i];
            atomicAdd(&hist[d2.x >> BKT_SHIFT], 1);
            atomicAdd(&hist[d2.y >> BKT_SHIFT], 1);
        } else {
            atomicAdd(&hist[dst[i] >> BKT_SHIFT], 1);
        }
    }
    __syncthreads();
    if (hist[t]) atomicAdd(&bktCnt[t], hist[t]);
}

// ---------------------------------------------------------------------------
// Stage 2: exclusive scan of NB_PAD bucket counts -> bktBase, init bktCursor.
// ---------------------------------------------------------------------------
__global__ __launch_bounds__(256) void bucket_scan_kernel(const int* __restrict__ bktCnt,
                                                          int* __restrict__ bktBase,
                                                          int* __restrict__ bktCursor) {
    __shared__ int wsum[4];
    int t = threadIdx.x;
    int own = bktCnt[t];
    int lane = t & 63, w = t >> 6;
    int inc = own;
    for (int d = 1; d < 64; d <<= 1) { int tt = __shfl_up(inc, d); if (lane >= d) inc += tt; }
    if (lane == 63) wsum[w] = inc;
    __syncthreads();
    if (t == 0) { int r = 0; for (int k = 0; k < 4; ++k) { int v = wsum[k]; wsum[k] = r; r += v; } }
    __syncthreads();
    int excl = (inc - own) + wsum[w];
    bktBase[t] = excl;
    bktCursor[t] = excl;
    if (t == 0) bktBase[NB_PAD] = 0;   // overwritten below for t==NB_PAD-1 case
    if (t == NB_PAD - 1) bktBase[NB_PAD] = excl + own;
}

// ---------------------------------------------------------------------------
// Stage 3: partition edges into per-bucket packed arrays:
// pk = (dstLocal << SRC_BITS) | src. LDS hist -> one global reservation per
// (block,bucket) -> LDS-rank writes. ~32-edge (128 B) runs per (block,bucket).
// ---------------------------------------------------------------------------
__global__ __launch_bounds__(256) void partition_kernel(const int* __restrict__ src,
                                                        const int* __restrict__ dst,
                                                        int* __restrict__ bktCursor,
                                                        unsigned* __restrict__ pairs, int nE) {
    __shared__ int hist[NB_PAD];
    __shared__ int lofs[NB_PAD];
    int t = threadIdx.x;
    hist[t] = 0;
    __syncthreads();
    int chunk = ((nE + PART_GRID - 1) / PART_GRID + 1) & ~1;
    int begin = blockIdx.x * chunk;
    int end = begin + chunk; if (end > nE) end = nE;
    for (int i = begin + 2 * t; i < end; i += 512) {
        if (i + 1 < end) {
            int2 d2 = *(const int2*)&dst[i];
            atomicAdd(&hist[d2.x >> BKT_SHIFT], 1);
            atomicAdd(&hist[d2.y >> BKT_SHIFT], 1);
        } else {
            atomicAdd(&hist[dst[i] >> BKT_SHIFT], 1);
        }
    }
    __syncthreads();
    int c = hist[t];
    lofs[t] = c ? atomicAdd(&bktCursor[t], c) : 0;
    __syncthreads();
    const unsigned LMASK = (1u << BKT_SHIFT) - 1u;
    for (int i = begin + 2 * t; i < end; i += 512) {
        if (i + 1 < end) {
            int2 d2 = *(const int2*)&dst[i];
            int2 s2 = *(const int2*)&src[i];
            int p0 = atomicAdd(&lofs[d2.x >> BKT_SHIFT], 1);
            pairs[p0] = (((unsigned)d2.x & LMASK) << SRC_BITS) | (unsigned)s2.x;
            int p1 = atomicAdd(&lofs[d2.y >> BKT_SHIFT], 1);
            pairs[p1] = (((unsigned)d2.y & LMASK) << SRC_BITS) | (unsigned)s2.y;
        } else {
            int d = dst[i];
            int pos = atomicAdd(&lofs[d >> BKT_SHIFT], 1);
            pairs[pos] = (((unsigned)d & LMASK) << SRC_BITS) | (unsigned)src[i];
        }
    }
}

// ---------------------------------------------------------------------------
// Stage 4: per-bucket CSR finalize (512-node buckets, 512-thread blocks).
// ---------------------------------------------------------------------------
__global__ __launch_bounds__(512) void csr_bucket_kernel(const unsigned* __restrict__ pairs,
                                                         const int* __restrict__ bktBase,
                                                         int* __restrict__ off,
                                                         int* __restrict__ csr,
                                                         int N, int E) {
    __shared__ int deg[512];
    __shared__ int cur[512];
    __shared__ int wsum[8];
    int b = blockIdx.x;
    int t = threadIdx.x;
    int lo = b << BKT_SHIFT;
    int nloc = N - lo; if (nloc > 512) nloc = 512;
    int e0 = bktBase[b], e1 = bktBase[b + 1];
    deg[t] = 0;
    __syncthreads();
    for (int e = e0 + t; e < e1; e += 512)
        atomicAdd(&deg[pairs[e] >> SRC_BITS], 1);
    __syncthreads();
    int v = deg[t];
    int lane = t & 63, w = t >> 6;
    int inc = v;
    for (int d = 1; d < 64; d <<= 1) { int tt = __shfl_up(inc, d); if (lane >= d) inc += tt; }
    if (lane == 63) wsum[w] = inc;
    __syncthreads();
    if (t == 0) { int r = 0; for (int k = 0; k < 8; ++k) { int x = wsum[k]; wsum[k] = r; r += x; } }
    __syncthreads();
    int excl = (inc - v) + wsum[w];
    if (t < nloc) off[lo + t] = e0 + excl;
    cur[t] = excl;
    if (b == 0 && t == 0) off[N] = E;
    __syncthreads();
    for (int e = e0 + t; e < e1; e += 512) {
        unsigned p = pairs[e];
        int pos = atomicAdd(&cur[p >> SRC_BITS], 1);
        csr[e0 + pos] = (int)(p & ((1u << SRC_BITS) - 1));
    }
}

// ---------------------------------------------------------------------------
// prep: Wl -> bf16, (Wr+Ws) -> bf16, bias = bl+bs (f32)
// ---------------------------------------------------------------------------
__global__ void prep_kernel(const float* __restrict__ Wl0, const float* __restrict__ Wr0,
                            const float* __restrict__ Ws0, const float* __restrict__ bl0,
                            const float* __restrict__ bs0,
                            const float* __restrict__ Wl1, const float* __restrict__ Wr1,
                            const float* __restrict__ Ws1, const float* __restrict__ bl1,
                            const float* __restrict__ bs1,
                            const float* __restrict__ Wl2, const float* __restrict__ Wr2,
                            const float* __restrict__ Ws2, const float* __restrict__ bl2,
                            const float* __restrict__ bs2,
                            unsigned short* __restrict__ wlb,
                            unsigned short* __restrict__ wcb,
                            float* __restrict__ bias) {
    int i = blockIdx.x * blockDim.x + threadIdx.x;
    if (i < 3 * FEAT * FEAT) {
        int li = i >> 12, j = i & 4095;
        const float* Wl = (li == 0) ? Wl0 : (li == 1) ? Wl1 : Wl2;
        const float* Wr = (li == 0) ? Wr0 : (li == 1) ? Wr1 : Wr2;
        const float* Ws = (li == 0) ? Ws0 : (li == 1) ? Ws1 : Ws2;
        wlb[i] = f2bf(Wl[j]);
        wcb[i] = f2bf(Wr[j] + Ws[j]);
    }
    if (i < 3 * FEAT) {
        int li = i >> 6, j = i & 63;
        const float* bl = (li == 0) ? bl0 : (li == 1) ? bl1 : bl2;
        const float* bs = (li == 0) ? bs0 : (li == 1) ? bs1 : bs2;
        bias[i] = bl[j] + bs[j];
    }
}

// ---------------------------------------------------------------------------
// x (f32) -> xb (bf16), 8 elems/thread
// ---------------------------------------------------------------------------
__global__ __launch_bounds__(256) void conv_kernel(const float* __restrict__ in,
                                                   unsigned short* __restrict__ outb,
                                                   int nElem) {
    int base = (blockIdx.x * blockDim.x + threadIdx.x) * 8;
    if (base >= nElem) return;
    float4 a = *(const float4*)(in + base);
    float4 b = *(const float4*)(in + base + 4);
    ushort4 p0 = {f2bf(a.x), f2bf(a.y), f2bf(a.z), f2bf(a.w)};
    ushort4 p1 = {f2bf(b.x), f2bf(b.y), f2bf(b.z), f2bf(b.w)};
    *(ushort4*)(outb + base) = p0;
    *(ushort4*)(outb + base + 4) = p1;
}

// ---------------------------------------------------------------------------
// Max-aggregation on bf16 rows (128 B/row): 8-lane group per node,
// 4 rows in flight per group (round-12 form — 8-deep regressed).
// ---------------------------------------------------------------------------
__global__ __launch_bounds__(256) void agg_kernel(const unsigned short* __restrict__ hb,
                                                  const int* __restrict__ off,
                                                  const int* __restrict__ csr_src,
                                                  unsigned short* __restrict__ ab,
                                                  int nNodes) {
    int gid = blockIdx.x * blockDim.x + threadIdx.x;
    int n = gid >> 3;
    int q = gid & 7;
    if (n >= nNodes) return;

    int e0 = off[n], e1 = off[n + 1];
    const float NEG = -INFINITY;
    float acc[8] = {NEG, NEG, NEG, NEG, NEG, NEG, NEG, NEG};

    int e = e0;
    for (; e + 4 <= e1; e += 4) {
        int s0 = csr_src[e], s1 = csr_src[e + 1], s2 = csr_src[e + 2], s3 = csr_src[e + 3];
        uint4 v0 = *(const uint4*)&hb[(size_t)s0 * FEAT + q * 8];
        uint4 v1 = *(const uint4*)&hb[(size_t)s1 * FEAT + q * 8];
        uint4 v2 = *(const uint4*)&hb[(size_t)s2 * FEAT + q * 8];
        uint4 v3 = *(const uint4*)&hb[(size_t)s3 * FEAT + q * 8];
#define ACCUM(v)                                            \
        acc[0] = fmaxf(acc[0], bf_lo(v.x)); acc[1] = fmaxf(acc[1], bf_hi(v.x)); \
        acc[2] = fmaxf(acc[2], bf_lo(v.y)); acc[3] = fmaxf(acc[3], bf_hi(v.y)); \
        acc[4] = fmaxf(acc[4], bf_lo(v.z)); acc[5] = fmaxf(acc[5], bf_hi(v.z)); \
        acc[6] = fmaxf(acc[6], bf_lo(v.w)); acc[7] = fmaxf(acc[7], bf_hi(v.w));
        ACCUM(v0) ACCUM(v1) ACCUM(v2) ACCUM(v3)
    }
    for (; e < e1; ++e) {
        int s0 = csr_src[e];
        uint4 v0 = *(const uint4*)&hb[(size_t)s0 * FEAT + q * 8];
        ACCUM(v0)
    }
#undef ACCUM

    uint4 outv;
    if (e1 > e0) {
        outv.x = pack_exact(acc[0], acc[1]);
        outv.y = pack_exact(acc[2], acc[3]);
        outv.z = pack_exact(acc[4], acc[5]);
        outv.w = pack_exact(acc[6], acc[7]);
    } else {
        outv = make_uint4(0, 0, 0, 0);
    }
    *(uint4*)&ab[(size_t)n * FEAT + q * 8] = outv;
}

// ---------------------------------------------------------------------------
// MFMA transform: out[n][f] = relu(sum_k agg[n][k]*Wl[f][k] + h[n][k]*Wc[f][k]
//                                  + bias[f]). Per 16-node tile: 4x
// mfma_f32_16x16x32_bf16, no LDS. C/D layout (guide m89): n=lane&15,
// f = f0 + (lane>>4)*4 + reg.
// ---------------------------------------------------------------------------
template <bool BF16OUT>
__global__ __launch_bounds__(256) void transform_mfma_kernel(
        const unsigned short* __restrict__ hb,
        const unsigned short* __restrict__ ab,
        const unsigned short* __restrict__ Wlb,
        const unsigned short* __restrict__ Wcb,
        const float* __restrict__ bias,
        float* __restrict__ outf,
        unsigned short* __restrict__ outb,
        int nNodes, int tpb, int nTiles) {
    int wave = threadIdx.x >> 6;
    int lane = threadIdx.x & 63;
    int f0 = wave << 4;
    int lm = lane & 15;
    int lk = lane >> 4;

    short8 aWl0 = *(const short8*)&Wlb[(f0 + lm) * FEAT + lk * 8];
    short8 aWl1 = *(const short8*)&Wlb[(f0 + lm) * FEAT + lk * 8 + 32];
    short8 aWc0 = *(const short8*)&Wcb[(f0 + lm) * FEAT + lk * 8];
    short8 aWc1 = *(const short8*)&Wcb[(f0 + lm) * FEAT + lk * 8 + 32];
    f32x4 b4 = *(const f32x4*)&bias[f0 + lk * 4];

    int t0 = blockIdx.x * tpb;
    int t1 = t0 + tpb; if (t1 > nTiles) t1 = nTiles;
#pragma unroll 2
    for (int t = t0; t < t1; ++t) {
        int nb = t << 4;
        int n = nb + lm;
        int nr = (n < nNodes) ? n : (nNodes - 1);
        const unsigned short* __restrict__ ar = ab + (size_t)nr * FEAT;
        const unsigned short* __restrict__ hr = hb + (size_t)nr * FEAT;
        short8 bA0 = *(const short8*)(ar + lk * 8);
        short8 bA1 = *(const short8*)(ar + lk * 8 + 32);
        short8 bH0 = *(const short8*)(hr + lk * 8);
        short8 bH1 = *(const short8*)(hr + lk * 8 + 32);

        f32x4 acc = {0.f, 0.f, 0.f, 0.f};
        acc = __builtin_amdgcn_mfma_f32_16x16x32_bf16(aWl0, bA0, acc, 0, 0, 0);
        acc = __builtin_amdgcn_mfma_f32_16x16x32_bf16(aWl1, bA1, acc, 0, 0, 0);
        acc = __builtin_amdgcn_mfma_f32_16x16x32_bf16(aWc0, bH0, acc, 0, 0, 0);
        acc = __builtin_amdgcn_mfma_f32_16x16x32_bf16(aWc1, bH1, acc, 0, 0, 0);

        if (n < nNodes) {
            float v0 = fmaxf(acc[0] + b4[0], 0.f);
            float v1 = fmaxf(acc[1] + b4[1], 0.f);
            float v2 = fmaxf(acc[2] + b4[2], 0.f);
            float v3 = fmaxf(acc[3] + b4[3], 0.f);
            if (BF16OUT) {
                ushort4 p = {f2bf(v0), f2bf(v1), f2bf(v2), f2bf(v3)};
                *(ushort4*)&outb[(size_t)n * FEAT + f0 + lk * 4] = p;
            } else {
                float4 p = make_float4(v0, v1, v2, v3);
                *(float4*)&outf[(size_t)n * FEAT + f0 + lk * 4] = p;
            }
        }
    }
}

// ---------------------------------------------------------------------------
extern "C" void kernel_launch(void* const* d_in, const int* in_sizes, int n_in,
                              void* d_out, int out_size, void* d_ws, size_t ws_size,
                              hipStream_t stream) {
    const float* x   = (const float*)d_in[0];
    const int* eidx  = (const int*)d_in[1];
    const int N  = in_sizes[0] / FEAT;
    const int E  = in_sizes[1] / 2;
    const int* src = eidx;
    const int* dst = eidx + E;

    const float* Wl[3]; const float* bl[3]; const float* Wr[3];
    const float* Ws[3]; const float* bs[3];
    for (int li = 0; li < 3; ++li) {
        Wl[li] = (const float*)d_in[2 + 5 * li + 0];
        bl[li] = (const float*)d_in[2 + 5 * li + 1];
        Wr[li] = (const float*)d_in[2 + 5 * li + 2];
        Ws[li] = (const float*)d_in[2 + 5 * li + 3];
        bs[li] = (const float*)d_in[2 + 5 * li + 4];
    }

    auto align256 = [](size_t v) { return (v + 255) & ~(size_t)255; };
    char* ws = (char*)d_ws;
    int* off       = (int*)ws;  ws += align256((size_t)(N + 1) * 4);
    int* bktCnt    = (int*)ws;  ws += align256(NB_PAD * 4);
    int* bktBase   = (int*)ws;  ws += align256((NB_PAD + 1) * 4);
    int* bktCursor = (int*)ws;  ws += align256(NB_PAD * 4);
    unsigned* pairs = (unsigned*)ws; ws += align256((size_t)E * 4);
    int* csr_src   = (int*)ws;  ws += align256((size_t)E * 4);
    unsigned short* wlb = (unsigned short*)ws; ws += align256(3 * FEAT * FEAT * 2);
    unsigned short* wcb = (unsigned short*)ws; ws += align256(3 * FEAT * FEAT * 2);
    float* biasbuf = (float*)ws; ws += align256(3 * FEAT * 4);
    unsigned short* xb  = (unsigned short*)ws; ws += align256((size_t)N * FEAT * 2);
    unsigned short* ab  = (unsigned short*)ws; ws += align256((size_t)N * FEAT * 2);
    unsigned short* h1b = (unsigned short*)ws; ws += align256((size_t)N * FEAT * 2);
    unsigned short* h2b = (unsigned short*)ws; ws += align256((size_t)N * FEAT * 2);

    const int TB = 256;
    int nBkt = (N + (1 << BKT_SHIFT) - 1) >> BKT_SHIFT;   // 196

    // ---- CSR build: hist -> scan -> partition -> per-bucket finalize ----
    zero_kernel<<<1, TB, 0, stream>>>(bktCnt, NB_PAD);
    hist_kernel<<<PART_GRID, TB, 0, stream>>>(dst, bktCnt, E);
    bucket_scan_kernel<<<1, TB, 0, stream>>>(bktCnt, bktBase, bktCursor);
    partition_kernel<<<PART_GRID, TB, 0, stream>>>(src, dst, bktCursor, pairs, E);
    csr_bucket_kernel<<<nBkt, 512, 0, stream>>>(pairs, bktBase, off, csr_src, N, E);

    prep_kernel<<<(3 * FEAT * FEAT + TB - 1) / TB, TB, 0, stream>>>(
        Wl[0], Wr[0], Ws[0], bl[0], bs[0],
        Wl[1], Wr[1], Ws[1], bl[1], bs[1],
        Wl[2], Wr[2], Ws[2], bl[2], bs[2], wlb, wcb, biasbuf);
    int convBlocks = (N * FEAT / 8 + TB - 1) / TB;
    conv_kernel<<<convBlocks, TB, 0, stream>>>(x, xb, N * FEAT);

    int aggBlocks = (N * 8 + TB - 1) / TB;
    int nTiles16 = (N + 15) / 16;
    const int TPB = 4;
    int trfBlocks = (nTiles16 + TPB - 1) / TPB;

    // ---- layer 0 ----
    agg_kernel<<<aggBlocks, TB, 0, stream>>>(xb, off, csr_src, ab, N);
    transform_mfma_kernel<true><<<trfBlocks, TB, 0, stream>>>(
        xb, ab, wlb + 0 * 4096, wcb + 0 * 4096, biasbuf + 0 * 64, nullptr, h1b, N, TPB, nTiles16);
    // ---- layer 1 ----
    agg_kernel<<<aggBlocks, TB, 0, stream>>>(h1b, off, csr_src, ab, N);
    transform_mfma_kernel<true><<<trfBlocks, TB, 0, stream>>>(
        h1b, ab, wlb + 1 * 4096, wcb + 1 * 4096, biasbuf + 1 * 64, nullptr, h2b, N, TPB, nTiles16);
    // ---- layer 2 (f32 output) ----
    agg_kernel<<<aggBlocks, TB, 0, stream>>>(h2b, off, csr_src, ab, N);
    transform_mfma_kernel<false><<<trfBlocks, TB, 0, stream>>>(
        h2b, ab, wlb + 2 * 4096, wcb + 2 * 4096, biasbuf + 2 * 64, (float*)d_out, nullptr, N, TPB, nTiles16);
}

// Round 15
// 207.971 us; speedup vs baseline: 1.1718x; 1.0039x over previous
//
#include <hip/hip_runtime.h>
#include <hip/hip_bf16.h>
#include <math.h>

#define FEAT 64
#define BKT_SHIFT 9          // 512 nodes per bucket
#define NB_PAD 256           // padded bucket count (ceil(100000/512)=196)
#define PART_GRID 256
#define SRC_BITS 17          // N <= 131072; dstLocal (9b) << 17 fits 26 bits

typedef __attribute__((ext_vector_type(8))) short short8;   // 8 bf16 (4 VGPRs)
typedef __attribute__((ext_vector_type(4))) float f32x4;    // MFMA C/D

// ---- bf16 helpers (RNE pack, exact unpack) --------------------------------
__device__ __forceinline__ float bf_lo(unsigned u) { return __uint_as_float(u << 16); }
__device__ __forceinline__ float bf_hi(unsigned u) { return __uint_as_float(u & 0xFFFF0000u); }
__device__ __forceinline__ unsigned short f2bf(float f) {
    unsigned b = __float_as_uint(f);
    return (unsigned short)((b + 0x7FFFu + ((b >> 16) & 1u)) >> 16);
}
__device__ __forceinline__ unsigned pack_exact(float lo, float hi) {
    return (__float_as_uint(lo) >> 16) | (__float_as_uint(hi) & 0xFFFF0000u);
}

// ---------------------------------------------------------------------------
// Stage 1: global bucket histogram (bucket = dst >> BKT_SHIFT), LDS hist.
// ---------------------------------------------------------------------------
__global__ __launch_bounds__(256) void hist_kernel(const int* __restrict__ dst,
                                                   int* __restrict__ bktCnt, int nE) {
    __shared__ int hist[NB_PAD];
    int t = threadIdx.x;
    hist[t] = 0;
    __syncthreads();
    int chunk = ((nE + PART_GRID - 1) / PART_GRID + 1) & ~1;
    int begin = blockIdx.x * chunk;
    int end = begin + chunk; if (end > nE) end = nE;
    for (int i = begin + 2 * t; i < end; i += 512) {
        if (i + 1 < end) {
            int2 d2 = *(const int2*)&dst[i];
            atomicAdd(&hist[d2.x >> BKT_SHIFT], 1);
            atomicAdd(&hist[d2.y >> BKT_SHIFT], 1);
        } else {
            atomicAdd(&hist[dst[i] >> BKT_SHIFT], 1);
        }
    }
    __syncthreads();
    if (hist[t]) atomicAdd(&bktCnt[t], hist[t]);
}

// ---------------------------------------------------------------------------
// Stage 2: scan of bucket counts -> exact bases (csr/off) + 64B-ALIGNED
// padded bases (pairs regions) + cursor init.
// pb[t] = roundup16(exact[t] + 16t): provably non-overlapping, run-aligned.
// ---------------------------------------------------------------------------
__global__ __launch_bounds__(256) void bucket_scan_kernel(const int* __restrict__ bktCnt,
                                                          int* __restrict__ baseC,
                                                          int* __restrict__ baseP,
                                                          int* __restrict__ bktCursor) {
    __shared__ int wsum[4];
    int t = threadIdx.x;
    int own = bktCnt[t];
    int lane = t & 63, w = t >> 6;
    int inc = own;
    for (int d = 1; d < 64; d <<= 1) { int tt = __shfl_up(inc, d); if (lane >= d) inc += tt; }
    if (lane == 63) wsum[w] = inc;
    __syncthreads();
    if (t == 0) { int r = 0; for (int k = 0; k < 4; ++k) { int v = wsum[k]; wsum[k] = r; r += v; } }
    __syncthreads();
    int excl = (inc - own) + wsum[w];
    baseC[t] = excl;
    int pb = (excl + 16 * t + 15) & ~15;
    baseP[t] = pb;
    bktCursor[t] = pb;
}

// ---------------------------------------------------------------------------
// Stage 3: partition edges into per-bucket packed arrays (64B-aligned runs):
// pk = (dstLocal << SRC_BITS) | src.
// ---------------------------------------------------------------------------
__global__ __launch_bounds__(256) void partition_kernel(const int* __restrict__ src,
                                                        const int* __restrict__ dst,
                                                        int* __restrict__ bktCursor,
                                                        unsigned* __restrict__ pairs, int nE) {
    __shared__ int hist[NB_PAD];
    __shared__ int lofs[NB_PAD];
    int t = threadIdx.x;
    hist[t] = 0;
    __syncthreads();
    int chunk = ((nE + PART_GRID - 1) / PART_GRID + 1) & ~1;
    int begin = blockIdx.x * chunk;
    int end = begin + chunk; if (end > nE) end = nE;
    for (int i = begin + 2 * t; i < end; i += 512) {
        if (i + 1 < end) {
            int2 d2 = *(const int2*)&dst[i];
            atomicAdd(&hist[d2.x >> BKT_SHIFT], 1);
            atomicAdd(&hist[d2.y >> BKT_SHIFT], 1);
        } else {
            atomicAdd(&hist[dst[i] >> BKT_SHIFT], 1);
        }
    }
    __syncthreads();
    int c = hist[t];
    lofs[t] = c ? atomicAdd(&bktCursor[t], c) : 0;
    __syncthreads();
    const unsigned LMASK = (1u << BKT_SHIFT) - 1u;
    for (int i = begin + 2 * t; i < end; i += 512) {
        if (i + 1 < end) {
            int2 d2 = *(const int2*)&dst[i];
            int2 s2 = *(const int2*)&src[i];
            int p0 = atomicAdd(&lofs[d2.x >> BKT_SHIFT], 1);
            pairs[p0] = (((unsigned)d2.x & LMASK) << SRC_BITS) | (unsigned)s2.x;
            int p1 = atomicAdd(&lofs[d2.y >> BKT_SHIFT], 1);
            pairs[p1] = (((unsigned)d2.y & LMASK) << SRC_BITS) | (unsigned)s2.y;
        } else {
            int d = dst[i];
            int pos = atomicAdd(&lofs[d >> BKT_SHIFT], 1);
            pairs[pos] = (((unsigned)d & LMASK) << SRC_BITS) | (unsigned)src[i];
        }
    }
}

// ---------------------------------------------------------------------------
// Stage 4: per-bucket CSR finalize (512-node buckets, 512-thread blocks).
// Reads pairs from padded base, writes off/csr from exact base.
// ---------------------------------------------------------------------------
__global__ __launch_bounds__(512) void csr_bucket_kernel(const unsigned* __restrict__ pairs,
                                                         const int* __restrict__ baseP,
                                                         const int* __restrict__ baseC,
                                                         const int* __restrict__ bktCnt,
                                                         int* __restrict__ off,
                                                         int* __restrict__ csr,
                                                         int N, int E) {
    __shared__ int deg[512];
    __shared__ int cur[512];
    __shared__ int wsum[8];
    int b = blockIdx.x;
    int t = threadIdx.x;
    int lo = b << BKT_SHIFT;
    int nloc = N - lo; if (nloc > 512) nloc = 512;
    int e0p = baseP[b];
    int e0c = baseC[b];
    int cnt = bktCnt[b];
    deg[t] = 0;
    __syncthreads();
    for (int e = t; e < cnt; e += 512)
        atomicAdd(&deg[pairs[e0p + e] >> SRC_BITS], 1);
    __syncthreads();
    int v = deg[t];
    int lane = t & 63, w = t >> 6;
    int inc = v;
    for (int d = 1; d < 64; d <<= 1) { int tt = __shfl_up(inc, d); if (lane >= d) inc += tt; }
    if (lane == 63) wsum[w] = inc;
    __syncthreads();
    if (t == 0) { int r = 0; for (int k = 0; k < 8; ++k) { int x = wsum[k]; wsum[k] = r; r += x; } }
    __syncthreads();
    int excl = (inc - v) + wsum[w];
    if (t < nloc) off[lo + t] = e0c + excl;
    cur[t] = excl;
    if (b == 0 && t == 0) off[N] = E;
    __syncthreads();
    for (int e = t; e < cnt; e += 512) {
        unsigned p = pairs[e0p + e];
        int pos = atomicAdd(&cur[p >> SRC_BITS], 1);
        csr[e0c + pos] = (int)(p & ((1u << SRC_BITS) - 1));
    }
}

// ---------------------------------------------------------------------------
// prep: Wl -> bf16, (Wr+Ws) -> bf16, bias = bl+bs (f32)
// ---------------------------------------------------------------------------
__global__ void prep_kernel(const float* __restrict__ Wl0, const float* __restrict__ Wr0,
                            const float* __restrict__ Ws0, const float* __restrict__ bl0,
                            const float* __restrict__ bs0,
                            const float* __restrict__ Wl1, const float* __restrict__ Wr1,
                            const float* __restrict__ Ws1, const float* __restrict__ bl1,
                            const float* __restrict__ bs1,
                            const float* __restrict__ Wl2, const float* __restrict__ Wr2,
                            const float* __restrict__ Ws2, const float* __restrict__ bl2,
                            const float* __restrict__ bs2,
                            unsigned short* __restrict__ wlb,
                            unsigned short* __restrict__ wcb,
                            float* __restrict__ bias) {
    int i = blockIdx.x * blockDim.x + threadIdx.x;
    if (i < 3 * FEAT * FEAT) {
        int li = i >> 12, j = i & 4095;
        const float* Wl = (li == 0) ? Wl0 : (li == 1) ? Wl1 : Wl2;
        const float* Wr = (li == 0) ? Wr0 : (li == 1) ? Wr1 : Wr2;
        const float* Ws = (li == 0) ? Ws0 : (li == 1) ? Ws1 : Ws2;
        wlb[i] = f2bf(Wl[j]);
        wcb[i] = f2bf(Wr[j] + Ws[j]);
    }
    if (i < 3 * FEAT) {
        int li = i >> 6, j = i & 63;
        const float* bl = (li == 0) ? bl0 : (li == 1) ? bl1 : bl2;
        const float* bs = (li == 0) ? bs0 : (li == 1) ? bs1 : bs2;
        bias[i] = bl[j] + bs[j];
    }
}

// ---------------------------------------------------------------------------
// x (f32) -> xb (bf16), 8 elems/thread
// ---------------------------------------------------------------------------
__global__ __launch_bounds__(256) void conv_kernel(const float* __restrict__ in,
                                                   unsigned short* __restrict__ outb,
                                                   int nElem) {
    int base = (blockIdx.x * blockDim.x + threadIdx.x) * 8;
    if (base >= nElem) return;
    float4 a = *(const float4*)(in + base);
    float4 b = *(const float4*)(in + base + 4);
    ushort4 p0 = {f2bf(a.x), f2bf(a.y), f2bf(a.z), f2bf(a.w)};
    ushort4 p1 = {f2bf(b.x), f2bf(b.y), f2bf(b.z), f2bf(b.w)};
    *(ushort4*)(outb + base) = p0;
    *(ushort4*)(outb + base + 4) = p1;
}

// ---------------------------------------------------------------------------
// Max-aggregation on bf16 rows (128 B/row): 8-lane group per node,
// 4 rows in flight per group.
// ---------------------------------------------------------------------------
__global__ __launch_bounds__(256) void agg_kernel(const unsigned short* __restrict__ hb,
                                                  const int* __restrict__ off,
                                                  const int* __restrict__ csr_src,
                                                  unsigned short* __restrict__ ab,
                                                  int nNodes) {
    int gid = blockIdx.x * blockDim.x + threadIdx.x;
    int n = gid >> 3;
    int q = gid & 7;
    if (n >= nNodes) return;

    int e0 = off[n], e1 = off[n + 1];
    const float NEG = -INFINITY;
    float acc[8] = {NEG, NEG, NEG, NEG, NEG, NEG, NEG, NEG};

    int e = e0;
    for (; e + 4 <= e1; e += 4) {
        int s0 = csr_src[e], s1 = csr_src[e + 1], s2 = csr_src[e + 2], s3 = csr_src[e + 3];
        uint4 v0 = *(const uint4*)&hb[(size_t)s0 * FEAT + q * 8];
        uint4 v1 = *(const uint4*)&hb[(size_t)s1 * FEAT + q * 8];
        uint4 v2 = *(const uint4*)&hb[(size_t)s2 * FEAT + q * 8];
        uint4 v3 = *(const uint4*)&hb[(size_t)s3 * FEAT + q * 8];
#define ACCUM(v)                                            \
        acc[0] = fmaxf(acc[0], bf_lo(v.x)); acc[1] = fmaxf(acc[1], bf_hi(v.x)); \
        acc[2] = fmaxf(acc[2], bf_lo(v.y)); acc[3] = fmaxf(acc[3], bf_hi(v.y)); \
        acc[4] = fmaxf(acc[4], bf_lo(v.z)); acc[5] = fmaxf(acc[5], bf_hi(v.z)); \
        acc[6] = fmaxf(acc[6], bf_lo(v.w)); acc[7] = fmaxf(acc[7], bf_hi(v.w));
        ACCUM(v0) ACCUM(v1) ACCUM(v2) ACCUM(v3)
    }
    for (; e < e1; ++e) {
        int s0 = csr_src[e];
        uint4 v0 = *(const uint4*)&hb[(size_t)s0 * FEAT + q * 8];
        ACCUM(v0)
    }
#undef ACCUM

    uint4 outv;
    if (e1 > e0) {
        outv.x = pack_exact(acc[0], acc[1]);
        outv.y = pack_exact(acc[2], acc[3]);
        outv.z = pack_exact(acc[4], acc[5]);
        outv.w = pack_exact(acc[6], acc[7]);
    } else {
        outv = make_uint4(0, 0, 0, 0);
    }
    *(uint4*)&ab[(size_t)n * FEAT + q * 8] = outv;
}

// ---------------------------------------------------------------------------
// MFMA transform: out[n][f] = relu(sum_k agg[n][k]*Wl[f][k] + h[n][k]*Wc[f][k]
//                                  + bias[f]). Per 16-node tile: 4x
// mfma_f32_16x16x32_bf16, no LDS. C/D layout (guide m89): n=lane&15,
// f = f0 + (lane>>4)*4 + reg.
// ---------------------------------------------------------------------------
template <bool BF16OUT>
__global__ __launch_bounds__(256) void transform_mfma_kernel(
        const unsigned short* __restrict__ hb,
        const unsigned short* __restrict__ ab,
        const unsigned short* __restrict__ Wlb,
        const unsigned short* __restrict__ Wcb,
        const float* __restrict__ bias,
        float* __restrict__ outf,
        unsigned short* __restrict__ outb,
        int nNodes, int tpb, int nTiles) {
    int wave = threadIdx.x >> 6;
    int lane = threadIdx.x & 63;
    int f0 = wave << 4;
    int lm = lane & 15;
    int lk = lane >> 4;

    short8 aWl0 = *(const short8*)&Wlb[(f0 + lm) * FEAT + lk * 8];
    short8 aWl1 = *(const short8*)&Wlb[(f0 + lm) * FEAT + lk * 8 + 32];
    short8 aWc0 = *(const short8*)&Wcb[(f0 + lm) * FEAT + lk * 8];
    short8 aWc1 = *(const short8*)&Wcb[(f0 + lm) * FEAT + lk * 8 + 32];
    f32x4 b4 = *(const f32x4*)&bias[f0 + lk * 4];

    int t0 = blockIdx.x * tpb;
    int t1 = t0 + tpb; if (t1 > nTiles) t1 = nTiles;
#pragma unroll 2
    for (int t = t0; t < t1; ++t) {
        int nb = t << 4;
        int n = nb + lm;
        int nr = (n < nNodes) ? n : (nNodes - 1);
        const unsigned short* __restrict__ ar = ab + (size_t)nr * FEAT;
        const unsigned short* __restrict__ hr = hb + (size_t)nr * FEAT;
        short8 bA0 = *(const short8*)(ar + lk * 8);
        short8 bA1 = *(const short8*)(ar + lk * 8 + 32);
        short8 bH0 = *(const short8*)(hr + lk * 8);
        short8 bH1 = *(const short8*)(hr + lk * 8 + 32);

        f32x4 acc = {0.f, 0.f, 0.f, 0.f};
        acc = __builtin_amdgcn_mfma_f32_16x16x32_bf16(aWl0, bA0, acc, 0, 0, 0);
        acc = __builtin_amdgcn_mfma_f32_16x16x32_bf16(aWl1, bA1, acc, 0, 0, 0);
        acc = __builtin_amdgcn_mfma_f32_16x16x32_bf16(aWc0, bH0, acc, 0, 0, 0);
        acc = __builtin_amdgcn_mfma_f32_16x16x32_bf16(aWc1, bH1, acc, 0, 0, 0);

        if (n < nNodes) {
            float v0 = fmaxf(acc[0] + b4[0], 0.f);
            float v1 = fmaxf(acc[1] + b4[1], 0.f);
            float v2 = fmaxf(acc[2] + b4[2], 0.f);
            float v3 = fmaxf(acc[3] + b4[3], 0.f);
            if (BF16OUT) {
                ushort4 p = {f2bf(v0), f2bf(v1), f2bf(v2), f2bf(v3)};
                *(ushort4*)&outb[(size_t)n * FEAT + f0 + lk * 4] = p;
            } else {
                float4 p = make_float4(v0, v1, v2, v3);
                *(float4*)&outf[(size_t)n * FEAT + f0 + lk * 4] = p;
            }
        }
    }
}

// ---------------------------------------------------------------------------
extern "C" void kernel_launch(void* const* d_in, const int* in_sizes, int n_in,
                              void* d_out, int out_size, void* d_ws, size_t ws_size,
                              hipStream_t stream) {
    const float* x   = (const float*)d_in[0];
    const int* eidx  = (const int*)d_in[1];
    const int N  = in_sizes[0] / FEAT;
    const int E  = in_sizes[1] / 2;
    const int* src = eidx;
    const int* dst = eidx + E;

    const float* Wl[3]; const float* bl[3]; const float* Wr[3];
    const float* Ws[3]; const float* bs[3];
    for (int li = 0; li < 3; ++li) {
        Wl[li] = (const float*)d_in[2 + 5 * li + 0];
        bl[li] = (const float*)d_in[2 + 5 * li + 1];
        Wr[li] = (const float*)d_in[2 + 5 * li + 2];
        Ws[li] = (const float*)d_in[2 + 5 * li + 3];
        bs[li] = (const float*)d_in[2 + 5 * li + 4];
    }

    auto align256 = [](size_t v) { return (v + 255) & ~(size_t)255; };
    char* ws = (char*)d_ws;
    int* off       = (int*)ws;  ws += align256((size_t)(N + 1) * 4);
    int* bktCnt    = (int*)ws;  ws += align256(NB_PAD * 4);
    int* baseC     = (int*)ws;  ws += align256((NB_PAD + 1) * 4);
    int* baseP     = (int*)ws;  ws += align256((NB_PAD + 1) * 4);
    int* bktCursor = (int*)ws;  ws += align256(NB_PAD * 4);
    unsigned* pairs = (unsigned*)ws; ws += align256(((size_t)E + 16 * NB_PAD + 64) * 4);
    int* csr_src   = (int*)ws;  ws += align256((size_t)E * 4);
    unsigned short* wlb = (unsigned short*)ws; ws += align256(3 * FEAT * FEAT * 2);
    unsigned short* wcb = (unsigned short*)ws; ws += align256(3 * FEAT * FEAT * 2);
    float* biasbuf = (float*)ws; ws += align256(3 * FEAT * 4);
    unsigned short* xb  = (unsigned short*)ws; ws += align256((size_t)N * FEAT * 2);
    unsigned short* ab  = (unsigned short*)ws; ws += align256((size_t)N * FEAT * 2);
    unsigned short* h1b = (unsigned short*)ws; ws += align256((size_t)N * FEAT * 2);
    unsigned short* h2b = (unsigned short*)ws; ws += align256((size_t)N * FEAT * 2);

    const int TB = 256;
    int nBkt = (N + (1 << BKT_SHIFT) - 1) >> BKT_SHIFT;   // 196

    // ---- CSR build: hist -> scan -> partition -> per-bucket finalize ----
    hipMemsetAsync(bktCnt, 0, NB_PAD * 4, stream);
    hist_kernel<<<PART_GRID, TB, 0, stream>>>(dst, bktCnt, E);
    bucket_scan_kernel<<<1, TB, 0, stream>>>(bktCnt, baseC, baseP, bktCursor);
    partition_kernel<<<PART_GRID, TB, 0, stream>>>(src, dst, bktCursor, pairs, E);
    csr_bucket_kernel<<<nBkt, 512, 0, stream>>>(pairs, baseP, baseC, bktCnt, off, csr_src, N, E);

    prep_kernel<<<(3 * FEAT * FEAT + TB - 1) / TB, TB, 0, stream>>>(
        Wl[0], Wr[0], Ws[0], bl[0], bs[0],
        Wl[1], Wr[1], Ws[1], bl[1], bs[1],
        Wl[2], Wr[2], Ws[2], bl[2], bs[2], wlb, wcb, biasbuf);
    int convBlocks = (N * FEAT / 8 + TB - 1) / TB;
    conv_kernel<<<convBlocks, TB, 0, stream>>>(x, xb, N * FEAT);

    int aggBlocks = (N * 8 + TB - 1) / TB;
    int nTiles16 = (N + 15) / 16;
    const int TPB = 4;
    int trfBlocks = (nTiles16 + TPB - 1) / TPB;

    // ---- layer 0 ----
    agg_kernel<<<aggBlocks, TB, 0, stream>>>(xb, off, csr_src, ab, N);
    transform_mfma_kernel<true><<<trfBlocks, TB, 0, stream>>>(
        xb, ab, wlb + 0 * 4096, wcb + 0 * 4096, biasbuf + 0 * 64, nullptr, h1b, N, TPB, nTiles16);
    // ---- layer 1 ----
    agg_kernel<<<aggBlocks, TB, 0, stream>>>(h1b, off, csr_src, ab, N);
    transform_mfma_kernel<true><<<trfBlocks, TB, 0, stream>>>(
        h1b, ab, wlb + 1 * 4096, wcb + 1 * 4096, biasbuf + 1 * 64, nullptr, h2b, N, TPB, nTiles16);
    // ---- layer 2 (f32 output) ----
    agg_kernel<<<aggBlocks, TB, 0, stream>>>(h2b, off, csr_src, ab, N);
    transform_mfma_kernel<false><<<trfBlocks, TB, 0, stream>>>(
        h2b, ab, wlb + 2 * 4096, wcb + 2 * 4096, biasbuf + 2 * 64, (float*)d_out, nullptr, N, TPB, nTiles16);
}

// Round 16
// 177.452 us; speedup vs baseline: 1.3733x; 1.1720x over previous
//
#include <hip/hip_runtime.h>
#include <hip/hip_bf16.h>
#include <math.h>

#define FEAT 64
#define BKT_SHIFT 9          // 512 nodes per bucket
#define NB_PAD 256           // padded bucket count (ceil(100000/512)=196)
#define PART_GRID 256
#define SRC_BITS 17          // N <= 131072; dstLocal (9b) << 17 fits 26 bits

typedef __attribute__((ext_vector_type(8))) short short8;   // 8 bf16 (4 VGPRs)
typedef __attribute__((ext_vector_type(4))) float f32x4;    // MFMA C/D

// ---- bf16 helpers (RNE pack, exact unpack) --------------------------------
__device__ __forceinline__ float bf_lo(unsigned u) { return __uint_as_float(u << 16); }
__device__ __forceinline__ float bf_hi(unsigned u) { return __uint_as_float(u & 0xFFFF0000u); }
__device__ __forceinline__ unsigned short f2bf(float f) {
    unsigned b = __float_as_uint(f);
    return (unsigned short)((b + 0x7FFFu + ((b >> 16) & 1u)) >> 16);
}
__device__ __forceinline__ unsigned pack_exact(float lo, float hi) {
    return (__float_as_uint(lo) >> 16) | (__float_as_uint(hi) & 0xFFFF0000u);
}

// ---------------------------------------------------------------------------
// Stage 1: global bucket histogram (bucket = dst >> BKT_SHIFT), LDS hist.
// ---------------------------------------------------------------------------
__global__ __launch_bounds__(256) void hist_kernel(const int* __restrict__ dst,
                                                   int* __restrict__ bktCnt, int nE) {
    __shared__ int hist[NB_PAD];
    int t = threadIdx.x;
    hist[t] = 0;
    __syncthreads();
    int chunk = ((nE + PART_GRID - 1) / PART_GRID + 1) & ~1;
    int begin = blockIdx.x * chunk;
    int end = begin + chunk; if (end > nE) end = nE;
    for (int i = begin + 2 * t; i < end; i += 512) {
        if (i + 1 < end) {
            int2 d2 = *(const int2*)&dst[i];
            atomicAdd(&hist[d2.x >> BKT_SHIFT], 1);
            atomicAdd(&hist[d2.y >> BKT_SHIFT], 1);
        } else {
            atomicAdd(&hist[dst[i] >> BKT_SHIFT], 1);
        }
    }
    __syncthreads();
    if (hist[t]) atomicAdd(&bktCnt[t], hist[t]);
}

// ---------------------------------------------------------------------------
// Stage 2: scan of bucket counts -> exact bases + padded (aligned) bases.
// ---------------------------------------------------------------------------
__global__ __launch_bounds__(256) void bucket_scan_kernel(const int* __restrict__ bktCnt,
                                                          int* __restrict__ baseC,
                                                          int* __restrict__ baseP,
                                                          int* __restrict__ bktCursor) {
    __shared__ int wsum[4];
    int t = threadIdx.x;
    int own = bktCnt[t];
    int lane = t & 63, w = t >> 6;
    int inc = own;
    for (int d = 1; d < 64; d <<= 1) { int tt = __shfl_up(inc, d); if (lane >= d) inc += tt; }
    if (lane == 63) wsum[w] = inc;
    __syncthreads();
    if (t == 0) { int r = 0; for (int k = 0; k < 4; ++k) { int v = wsum[k]; wsum[k] = r; r += v; } }
    __syncthreads();
    int excl = (inc - own) + wsum[w];
    baseC[t] = excl;
    int pb = (excl + 16 * t + 15) & ~15;
    baseP[t] = pb;
    bktCursor[t] = pb;
}

// ---------------------------------------------------------------------------
// Stage 3: partition edges into per-bucket packed arrays (64B-aligned runs):
// pk = (dstLocal << SRC_BITS) | src.
// ---------------------------------------------------------------------------
__global__ __launch_bounds__(256) void partition_kernel(const int* __restrict__ src,
                                                        const int* __restrict__ dst,
                                                        int* __restrict__ bktCursor,
                                                        unsigned* __restrict__ pairs, int nE) {
    __shared__ int hist[NB_PAD];
    __shared__ int lofs[NB_PAD];
    int t = threadIdx.x;
    hist[t] = 0;
    __syncthreads();
    int chunk = ((nE + PART_GRID - 1) / PART_GRID + 1) & ~1;
    int begin = blockIdx.x * chunk;
    int end = begin + chunk; if (end > nE) end = nE;
    for (int i = begin + 2 * t; i < end; i += 512) {
        if (i + 1 < end) {
            int2 d2 = *(const int2*)&dst[i];
            atomicAdd(&hist[d2.x >> BKT_SHIFT], 1);
            atomicAdd(&hist[d2.y >> BKT_SHIFT], 1);
        } else {
            atomicAdd(&hist[dst[i] >> BKT_SHIFT], 1);
        }
    }
    __syncthreads();
    int c = hist[t];
    lofs[t] = c ? atomicAdd(&bktCursor[t], c) : 0;
    __syncthreads();
    const unsigned LMASK = (1u << BKT_SHIFT) - 1u;
    for (int i = begin + 2 * t; i < end; i += 512) {
        if (i + 1 < end) {
            int2 d2 = *(const int2*)&dst[i];
            int2 s2 = *(const int2*)&src[i];
            int p0 = atomicAdd(&lofs[d2.x >> BKT_SHIFT], 1);
            pairs[p0] = (((unsigned)d2.x & LMASK) << SRC_BITS) | (unsigned)s2.x;
            int p1 = atomicAdd(&lofs[d2.y >> BKT_SHIFT], 1);
            pairs[p1] = (((unsigned)d2.y & LMASK) << SRC_BITS) | (unsigned)s2.y;
        } else {
            int d = dst[i];
            int pos = atomicAdd(&lofs[d >> BKT_SHIFT], 1);
            pairs[pos] = (((unsigned)d & LMASK) << SRC_BITS) | (unsigned)src[i];
        }
    }
}

// ---------------------------------------------------------------------------
// Stage 4: per-bucket CSR finalize (512-node buckets, 512-thread blocks).
// ---------------------------------------------------------------------------
__global__ __launch_bounds__(512) void csr_bucket_kernel(const unsigned* __restrict__ pairs,
                                                         const int* __restrict__ baseP,
                                                         const int* __restrict__ baseC,
                                                         const int* __restrict__ bktCnt,
                                                         int* __restrict__ off,
                                                         int* __restrict__ csr,
                                                         int N, int E) {
    __shared__ int deg[512];
    __shared__ int cur[512];
    __shared__ int wsum[8];
    int b = blockIdx.x;
    int t = threadIdx.x;
    int lo = b << BKT_SHIFT;
    int nloc = N - lo; if (nloc > 512) nloc = 512;
    int e0p = baseP[b];
    int e0c = baseC[b];
    int cnt = bktCnt[b];
    deg[t] = 0;
    __syncthreads();
    for (int e = t; e < cnt; e += 512)
        atomicAdd(&deg[pairs[e0p + e] >> SRC_BITS], 1);
    __syncthreads();
    int v = deg[t];
    int lane = t & 63, w = t >> 6;
    int inc = v;
    for (int d = 1; d < 64; d <<= 1) { int tt = __shfl_up(inc, d); if (lane >= d) inc += tt; }
    if (lane == 63) wsum[w] = inc;
    __syncthreads();
    if (t == 0) { int r = 0; for (int k = 0; k < 8; ++k) { int x = wsum[k]; wsum[k] = r; r += x; } }
    __syncthreads();
    int excl = (inc - v) + wsum[w];
    if (t < nloc) off[lo + t] = e0c + excl;
    cur[t] = excl;
    if (b == 0 && t == 0) off[N] = E;
    __syncthreads();
    for (int e = t; e < cnt; e += 512) {
        unsigned p = pairs[e0p + e];
        int pos = atomicAdd(&cur[p >> SRC_BITS], 1);
        csr[e0c + pos] = (int)(p & ((1u << SRC_BITS) - 1));
    }
}

// ---------------------------------------------------------------------------
// prep: Wl -> bf16, (Wr+Ws) -> bf16, bias = bl+bs (f32)
// ---------------------------------------------------------------------------
__global__ void prep_kernel(const float* __restrict__ Wl0, const float* __restrict__ Wr0,
                            const float* __restrict__ Ws0, const float* __restrict__ bl0,
                            const float* __restrict__ bs0,
                            const float* __restrict__ Wl1, const float* __restrict__ Wr1,
                            const float* __restrict__ Ws1, const float* __restrict__ bl1,
                            const float* __restrict__ bs1,
                            const float* __restrict__ Wl2, const float* __restrict__ Wr2,
                            const float* __restrict__ Ws2, const float* __restrict__ bl2,
                            const float* __restrict__ bs2,
                            unsigned short* __restrict__ wlb,
                            unsigned short* __restrict__ wcb,
                            float* __restrict__ bias) {
    int i = blockIdx.x * blockDim.x + threadIdx.x;
    if (i < 3 * FEAT * FEAT) {
        int li = i >> 12, j = i & 4095;
        const float* Wl = (li == 0) ? Wl0 : (li == 1) ? Wl1 : Wl2;
        const float* Wr = (li == 0) ? Wr0 : (li == 1) ? Wr1 : Wr2;
        const float* Ws = (li == 0) ? Ws0 : (li == 1) ? Ws1 : Ws2;
        wlb[i] = f2bf(Wl[j]);
        wcb[i] = f2bf(Wr[j] + Ws[j]);
    }
    if (i < 3 * FEAT) {
        int li = i >> 6, j = i & 63;
        const float* bl = (li == 0) ? bl0 : (li == 1) ? bl1 : bl2;
        const float* bs = (li == 0) ? bs0 : (li == 1) ? bs1 : bs2;
        bias[i] = bl[j] + bs[j];
    }
}

// ---------------------------------------------------------------------------
// x (f32) -> xb (bf16), 8 elems/thread
// ---------------------------------------------------------------------------
__global__ __launch_bounds__(256) void conv_kernel(const float* __restrict__ in,
                                                   unsigned short* __restrict__ outb,
                                                   int nElem) {
    int base = (blockIdx.x * blockDim.x + threadIdx.x) * 8;
    if (base >= nElem) return;
    float4 a = *(const float4*)(in + base);
    float4 b = *(const float4*)(in + base + 4);
    ushort4 p0 = {f2bf(a.x), f2bf(a.y), f2bf(a.z), f2bf(a.w)};
    ushort4 p1 = {f2bf(b.x), f2bf(b.y), f2bf(b.z), f2bf(b.w)};
    *(ushort4*)(outb + base) = p0;
    *(ushort4*)(outb + base + 4) = p1;
}

// ---------------------------------------------------------------------------
// Fused layer: phase 1 max-aggregates 64 nodes into LDS (XOR-swizzled
// 16B chunks: stored chunk index = c ^ (nodeLocal & 7) — applied identically
// on write and read, avoiding the 128B-stride column-read bank conflict).
// Phase 2: MFMA transform; agg B-frag from LDS, h B-frag + weights from
// global. Saves the 12.8 MB agg round trip per layer + one dispatch.
// ---------------------------------------------------------------------------
template <bool BF16OUT>
__global__ __launch_bounds__(256) void fused_layer_kernel(
        const unsigned short* __restrict__ hb,
        const int* __restrict__ off,
        const int* __restrict__ csr_src,
        const unsigned short* __restrict__ Wlb,
        const unsigned short* __restrict__ Wcb,
        const float* __restrict__ bias,
        float* __restrict__ outf,
        unsigned short* __restrict__ outb,
        int nNodes) {
    __shared__ __align__(16) unsigned short agg_s[64 * FEAT];   // 8 KB

    int t = threadIdx.x;
    int nb0 = blockIdx.x * 64;

    // ---- phase 1: gather-max 64 nodes (32 groups x 8 lanes, 2 nodes each) --
    int g = t >> 3;
    int q = t & 7;
#pragma unroll
    for (int rep = 0; rep < 2; ++rep) {
        int nl = rep * 32 + g;
        int n = nb0 + nl;
        uint4 outv = make_uint4(0, 0, 0, 0);
        if (n < nNodes) {
            int e0 = off[n], e1 = off[n + 1];
            if (e1 > e0) {
                const float NEG = -INFINITY;
                float acc[8] = {NEG, NEG, NEG, NEG, NEG, NEG, NEG, NEG};
#define ACCUM(v)                                                            \
                acc[0] = fmaxf(acc[0], bf_lo(v.x)); acc[1] = fmaxf(acc[1], bf_hi(v.x)); \
                acc[2] = fmaxf(acc[2], bf_lo(v.y)); acc[3] = fmaxf(acc[3], bf_hi(v.y)); \
                acc[4] = fmaxf(acc[4], bf_lo(v.z)); acc[5] = fmaxf(acc[5], bf_hi(v.z)); \
                acc[6] = fmaxf(acc[6], bf_lo(v.w)); acc[7] = fmaxf(acc[7], bf_hi(v.w));
                int e = e0;
                for (; e + 4 <= e1; e += 4) {
                    int s0 = csr_src[e],     s1 = csr_src[e + 1];
                    int s2 = csr_src[e + 2], s3 = csr_src[e + 3];
                    uint4 v0 = *(const uint4*)&hb[(size_t)s0 * FEAT + q * 8];
                    uint4 v1 = *(const uint4*)&hb[(size_t)s1 * FEAT + q * 8];
                    uint4 v2 = *(const uint4*)&hb[(size_t)s2 * FEAT + q * 8];
                    uint4 v3 = *(const uint4*)&hb[(size_t)s3 * FEAT + q * 8];
                    ACCUM(v0) ACCUM(v1) ACCUM(v2) ACCUM(v3)
                }
                for (; e < e1; ++e) {
                    int s0 = csr_src[e];
                    uint4 v0 = *(const uint4*)&hb[(size_t)s0 * FEAT + q * 8];
                    ACCUM(v0)
                }
#undef ACCUM
                outv.x = pack_exact(acc[0], acc[1]);
                outv.y = pack_exact(acc[2], acc[3]);
                outv.z = pack_exact(acc[4], acc[5]);
                outv.w = pack_exact(acc[6], acc[7]);
            }
        }
        *(uint4*)&agg_s[nl * FEAT + ((q ^ (nl & 7)) << 3)] = outv;   // swizzled
    }
    __syncthreads();

    // ---- phase 2: MFMA transform (wave = f-quarter, 4 tiles of 16 nodes) --
    int wave = t >> 6, lane = t & 63;
    int f0 = wave << 4, lm = lane & 15, lk = lane >> 4;

    short8 aWl0 = *(const short8*)&Wlb[(f0 + lm) * FEAT + lk * 8];
    short8 aWl1 = *(const short8*)&Wlb[(f0 + lm) * FEAT + lk * 8 + 32];
    short8 aWc0 = *(const short8*)&Wcb[(f0 + lm) * FEAT + lk * 8];
    short8 aWc1 = *(const short8*)&Wcb[(f0 + lm) * FEAT + lk * 8 + 32];
    f32x4 b4 = *(const f32x4*)&bias[f0 + lk * 4];

#pragma unroll
    for (int tile = 0; tile < 4; ++tile) {
        int nl = tile * 16 + lm;
        int n = nb0 + nl;
        int nr = (n < nNodes) ? n : (nNodes - 1);
        const unsigned short* __restrict__ hr = hb + (size_t)nr * FEAT;
        short8 bA0 = *(const short8*)&agg_s[nl * FEAT + (((lk)     ^ (nl & 7)) << 3)];
        short8 bA1 = *(const short8*)&agg_s[nl * FEAT + (((lk + 4) ^ (nl & 7)) << 3)];
        short8 bH0 = *(const short8*)(hr + lk * 8);
        short8 bH1 = *(const short8*)(hr + lk * 8 + 32);

        f32x4 acc = {0.f, 0.f, 0.f, 0.f};
        acc = __builtin_amdgcn_mfma_f32_16x16x32_bf16(aWl0, bA0, acc, 0, 0, 0);
        acc = __builtin_amdgcn_mfma_f32_16x16x32_bf16(aWl1, bA1, acc, 0, 0, 0);
        acc = __builtin_amdgcn_mfma_f32_16x16x32_bf16(aWc0, bH0, acc, 0, 0, 0);
        acc = __builtin_amdgcn_mfma_f32_16x16x32_bf16(aWc1, bH1, acc, 0, 0, 0);

        if (n < nNodes) {
            float v0 = fmaxf(acc[0] + b4[0], 0.f);
            float v1 = fmaxf(acc[1] + b4[1], 0.f);
            float v2 = fmaxf(acc[2] + b4[2], 0.f);
            float v3 = fmaxf(acc[3] + b4[3], 0.f);
            if (BF16OUT) {
                ushort4 p = {f2bf(v0), f2bf(v1), f2bf(v2), f2bf(v3)};
                *(ushort4*)&outb[(size_t)n * FEAT + f0 + lk * 4] = p;
            } else {
                float4 p = make_float4(v0, v1, v2, v3);
                *(float4*)&outf[(size_t)n * FEAT + f0 + lk * 4] = p;
            }
        }
    }
}

// ---------------------------------------------------------------------------
extern "C" void kernel_launch(void* const* d_in, const int* in_sizes, int n_in,
                              void* d_out, int out_size, void* d_ws, size_t ws_size,
                              hipStream_t stream) {
    const float* x   = (const float*)d_in[0];
    const int* eidx  = (const int*)d_in[1];
    const int N  = in_sizes[0] / FEAT;
    const int E  = in_sizes[1] / 2;
    const int* src = eidx;
    const int* dst = eidx + E;

    const float* Wl[3]; const float* bl[3]; const float* Wr[3];
    const float* Ws[3]; const float* bs[3];
    for (int li = 0; li < 3; ++li) {
        Wl[li] = (const float*)d_in[2 + 5 * li + 0];
        bl[li] = (const float*)d_in[2 + 5 * li + 1];
        Wr[li] = (const float*)d_in[2 + 5 * li + 2];
        Ws[li] = (const float*)d_in[2 + 5 * li + 3];
        bs[li] = (const float*)d_in[2 + 5 * li + 4];
    }

    auto align256 = [](size_t v) { return (v + 255) & ~(size_t)255; };
    char* ws = (char*)d_ws;
    int* off       = (int*)ws;  ws += align256((size_t)(N + 1) * 4);
    int* bktCnt    = (int*)ws;  ws += align256(NB_PAD * 4);
    int* baseC     = (int*)ws;  ws += align256((NB_PAD + 1) * 4);
    int* baseP     = (int*)ws;  ws += align256((NB_PAD + 1) * 4);
    int* bktCursor = (int*)ws;  ws += align256(NB_PAD * 4);
    unsigned* pairs = (unsigned*)ws; ws += align256(((size_t)E + 16 * NB_PAD + 64) * 4);
    int* csr_src   = (int*)ws;  ws += align256((size_t)E * 4);
    unsigned short* wlb = (unsigned short*)ws; ws += align256(3 * FEAT * FEAT * 2);
    unsigned short* wcb = (unsigned short*)ws; ws += align256(3 * FEAT * FEAT * 2);
    float* biasbuf = (float*)ws; ws += align256(3 * FEAT * 4);
    unsigned short* xb  = (unsigned short*)ws; ws += align256((size_t)N * FEAT * 2);
    unsigned short* h1b = (unsigned short*)ws; ws += align256((size_t)N * FEAT * 2);
    unsigned short* h2b = (unsigned short*)ws; ws += align256((size_t)N * FEAT * 2);

    const int TB = 256;
    int nBkt = (N + (1 << BKT_SHIFT) - 1) >> BKT_SHIFT;   // 196

    // ---- CSR build: hist -> scan -> partition -> per-bucket finalize ----
    hipMemsetAsync(bktCnt, 0, NB_PAD * 4, stream);
    hist_kernel<<<PART_GRID, TB, 0, stream>>>(dst, bktCnt, E);
    bucket_scan_kernel<<<1, TB, 0, stream>>>(bktCnt, baseC, baseP, bktCursor);
    partition_kernel<<<PART_GRID, TB, 0, stream>>>(src, dst, bktCursor, pairs, E);
    csr_bucket_kernel<<<nBkt, 512, 0, stream>>>(pairs, baseP, baseC, bktCnt, off, csr_src, N, E);

    prep_kernel<<<(3 * FEAT * FEAT + TB - 1) / TB, TB, 0, stream>>>(
        Wl[0], Wr[0], Ws[0], bl[0], bs[0],
        Wl[1], Wr[1], Ws[1], bl[1], bs[1],
        Wl[2], Wr[2], Ws[2], bl[2], bs[2], wlb, wcb, biasbuf);
    int convBlocks = (N * FEAT / 8 + TB - 1) / TB;
    conv_kernel<<<convBlocks, TB, 0, stream>>>(x, xb, N * FEAT);

    int fusedBlocks = (N + 63) / 64;

    // ---- layer 0 ----
    fused_layer_kernel<true><<<fusedBlocks, TB, 0, stream>>>(
        xb, off, csr_src, wlb + 0 * 4096, wcb + 0 * 4096, biasbuf + 0 * 64,
        nullptr, h1b, N);
    // ---- layer 1 ----
    fused_layer_kernel<true><<<fusedBlocks, TB, 0, stream>>>(
        h1b, off, csr_src, wlb + 1 * 4096, wcb + 1 * 4096, biasbuf + 1 * 64,
        nullptr, h2b, N);
    // ---- layer 2 (f32 output) ----
    fused_layer_kernel<false><<<fusedBlocks, TB, 0, stream>>>(
        h2b, off, csr_src, wlb + 2 * 4096, wcb + 2 * 4096, biasbuf + 2 * 64,
        (float*)d_out, nullptr, N);
}

// Round 17
// 172.726 us; speedup vs baseline: 1.4109x; 1.0274x over previous
//
#include <hip/hip_runtime.h>
#include <hip/hip_bf16.h>
#include <math.h>

#define FEAT 64
#define BKT_SHIFT 9          // 512 nodes per bucket
#define NB_PAD 256           // padded bucket count (ceil(100000/512)=196)
#define PART_GRID 256        // #blocks fixes run length (write-merge); threads give latency hiding
#define PART_TB 1024
#define SRC_BITS 17          // N <= 131072; dstLocal (9b) << 17 fits 26 bits

typedef __attribute__((ext_vector_type(8))) short short8;   // 8 bf16 (4 VGPRs)
typedef __attribute__((ext_vector_type(4))) float f32x4;    // MFMA C/D

// ---- bf16 helpers (RNE pack, exact unpack) --------------------------------
__device__ __forceinline__ float bf_lo(unsigned u) { return __uint_as_float(u << 16); }
__device__ __forceinline__ float bf_hi(unsigned u) { return __uint_as_float(u & 0xFFFF0000u); }
__device__ __forceinline__ unsigned short f2bf(float f) {
    unsigned b = __float_as_uint(f);
    return (unsigned short)((b + 0x7FFFu + ((b >> 16) & 1u)) >> 16);
}
__device__ __forceinline__ unsigned pack_exact(float lo, float hi) {
    return (__float_as_uint(lo) >> 16) | (__float_as_uint(hi) & 0xFFFF0000u);
}

// ---------------------------------------------------------------------------
// Stage 1: global bucket histogram (bucket = dst >> BKT_SHIFT), LDS hist.
// 1024 threads/block: 4x latency hiding at identical chunking.
// ---------------------------------------------------------------------------
__global__ __launch_bounds__(PART_TB) void hist_kernel(const int* __restrict__ dst,
                                                       int* __restrict__ bktCnt, int nE) {
    __shared__ int hist[NB_PAD];
    int t = threadIdx.x;
    if (t < NB_PAD) hist[t] = 0;
    __syncthreads();
    int chunk = ((nE + PART_GRID - 1) / PART_GRID + 1) & ~1;
    int begin = blockIdx.x * chunk;
    int end = begin + chunk; if (end > nE) end = nE;
    for (int i = begin + 2 * t; i < end; i += 2 * PART_TB) {
        if (i + 1 < end) {
            int2 d2 = *(const int2*)&dst[i];
            atomicAdd(&hist[d2.x >> BKT_SHIFT], 1);
            atomicAdd(&hist[d2.y >> BKT_SHIFT], 1);
        } else {
            atomicAdd(&hist[dst[i] >> BKT_SHIFT], 1);
        }
    }
    __syncthreads();
    if (t < NB_PAD && hist[t]) atomicAdd(&bktCnt[t], hist[t]);
}

// ---------------------------------------------------------------------------
// Stage 2: scan of bucket counts -> exact bases + padded (aligned) bases.
// ---------------------------------------------------------------------------
__global__ __launch_bounds__(256) void bucket_scan_kernel(const int* __restrict__ bktCnt,
                                                          int* __restrict__ baseC,
                                                          int* __restrict__ baseP,
                                                          int* __restrict__ bktCursor) {
    __shared__ int wsum[4];
    int t = threadIdx.x;
    int own = bktCnt[t];
    int lane = t & 63, w = t >> 6;
    int inc = own;
    for (int d = 1; d < 64; d <<= 1) { int tt = __shfl_up(inc, d); if (lane >= d) inc += tt; }
    if (lane == 63) wsum[w] = inc;
    __syncthreads();
    if (t == 0) { int r = 0; for (int k = 0; k < 4; ++k) { int v = wsum[k]; wsum[k] = r; r += v; } }
    __syncthreads();
    int excl = (inc - own) + wsum[w];
    baseC[t] = excl;
    int pb = (excl + 16 * t + 15) & ~15;
    baseP[t] = pb;
    bktCursor[t] = pb;
}

// ---------------------------------------------------------------------------
// Stage 3: partition edges into per-bucket packed arrays (aligned runs):
// pk = (dstLocal << SRC_BITS) | src. 1024 threads/block.
// ---------------------------------------------------------------------------
__global__ __launch_bounds__(PART_TB) void partition_kernel(const int* __restrict__ src,
                                                            const int* __restrict__ dst,
                                                            int* __restrict__ bktCursor,
                                                            unsigned* __restrict__ pairs, int nE) {
    __shared__ int hist[NB_PAD];
    __shared__ int lofs[NB_PAD];
    int t = threadIdx.x;
    if (t < NB_PAD) hist[t] = 0;
    __syncthreads();
    int chunk = ((nE + PART_GRID - 1) / PART_GRID + 1) & ~1;
    int begin = blockIdx.x * chunk;
    int end = begin + chunk; if (end > nE) end = nE;
    for (int i = begin + 2 * t; i < end; i += 2 * PART_TB) {
        if (i + 1 < end) {
            int2 d2 = *(const int2*)&dst[i];
            atomicAdd(&hist[d2.x >> BKT_SHIFT], 1);
            atomicAdd(&hist[d2.y >> BKT_SHIFT], 1);
        } else {
            atomicAdd(&hist[dst[i] >> BKT_SHIFT], 1);
        }
    }
    __syncthreads();
    if (t < NB_PAD) {
        int c = hist[t];
        lofs[t] = c ? atomicAdd(&bktCursor[t], c) : 0;
    }
    __syncthreads();
    const unsigned LMASK = (1u << BKT_SHIFT) - 1u;
    for (int i = begin + 2 * t; i < end; i += 2 * PART_TB) {
        if (i + 1 < end) {
            int2 d2 = *(const int2*)&dst[i];
            int2 s2 = *(const int2*)&src[i];
            int p0 = atomicAdd(&lofs[d2.x >> BKT_SHIFT], 1);
            pairs[p0] = (((unsigned)d2.x & LMASK) << SRC_BITS) | (unsigned)s2.x;
            int p1 = atomicAdd(&lofs[d2.y >> BKT_SHIFT], 1);
            pairs[p1] = (((unsigned)d2.y & LMASK) << SRC_BITS) | (unsigned)s2.y;
        } else {
            int d = dst[i];
            int pos = atomicAdd(&lofs[d >> BKT_SHIFT], 1);
            pairs[pos] = (((unsigned)d & LMASK) << SRC_BITS) | (unsigned)src[i];
        }
    }
}

// ---------------------------------------------------------------------------
// Stage 4: per-bucket CSR finalize (512-node buckets, 512-thread blocks).
// ---------------------------------------------------------------------------
__global__ __launch_bounds__(512) void csr_bucket_kernel(const unsigned* __restrict__ pairs,
                                                         const int* __restrict__ baseP,
                                                         const int* __restrict__ baseC,
                                                         const int* __restrict__ bktCnt,
                                                         int* __restrict__ off,
                                                         int* __restrict__ csr,
                                                         int N, int E) {
    __shared__ int deg[512];
    __shared__ int cur[512];
    __shared__ int wsum[8];
    int b = blockIdx.x;
    int t = threadIdx.x;
    int lo = b << BKT_SHIFT;
    int nloc = N - lo; if (nloc > 512) nloc = 512;
    int e0p = baseP[b];
    int e0c = baseC[b];
    int cnt = bktCnt[b];
    deg[t] = 0;
    __syncthreads();
    for (int e = t; e < cnt; e += 512)
        atomicAdd(&deg[pairs[e0p + e] >> SRC_BITS], 1);
    __syncthreads();
    int v = deg[t];
    int lane = t & 63, w = t >> 6;
    int inc = v;
    for (int d = 1; d < 64; d <<= 1) { int tt = __shfl_up(inc, d); if (lane >= d) inc += tt; }
    if (lane == 63) wsum[w] = inc;
    __syncthreads();
    if (t == 0) { int r = 0; for (int k = 0; k < 8; ++k) { int x = wsum[k]; wsum[k] = r; r += x; } }
    __syncthreads();
    int excl = (inc - v) + wsum[w];
    if (t < nloc) off[lo + t] = e0c + excl;
    cur[t] = excl;
    if (b == 0 && t == 0) off[N] = E;
    __syncthreads();
    for (int e = t; e < cnt; e += 512) {
        unsigned p = pairs[e0p + e];
        int pos = atomicAdd(&cur[p >> SRC_BITS], 1);
        csr[e0c + pos] = (int)(p & ((1u << SRC_BITS) - 1));
    }
}

// ---------------------------------------------------------------------------
// prep: Wl -> bf16, (Wr+Ws) -> bf16, bias = bl+bs (f32)
// ---------------------------------------------------------------------------
__global__ void prep_kernel(const float* __restrict__ Wl0, const float* __restrict__ Wr0,
                            const float* __restrict__ Ws0, const float* __restrict__ bl0,
                            const float* __restrict__ bs0,
                            const float* __restrict__ Wl1, const float* __restrict__ Wr1,
                            const float* __restrict__ Ws1, const float* __restrict__ bl1,
                            const float* __restrict__ bs1,
                            const float* __restrict__ Wl2, const float* __restrict__ Wr2,
                            const float* __restrict__ Ws2, const float* __restrict__ bl2,
                            const float* __restrict__ bs2,
                            unsigned short* __restrict__ wlb,
                            unsigned short* __restrict__ wcb,
                            float* __restrict__ bias) {
    int i = blockIdx.x * blockDim.x + threadIdx.x;
    if (i < 3 * FEAT * FEAT) {
        int li = i >> 12, j = i & 4095;
        const float* Wl = (li == 0) ? Wl0 : (li == 1) ? Wl1 : Wl2;
        const float* Wr = (li == 0) ? Wr0 : (li == 1) ? Wr1 : Wr2;
        const float* Ws = (li == 0) ? Ws0 : (li == 1) ? Ws1 : Ws2;
        wlb[i] = f2bf(Wl[j]);
        wcb[i] = f2bf(Wr[j] + Ws[j]);
    }
    if (i < 3 * FEAT) {
        int li = i >> 6, j = i & 63;
        const float* bl = (li == 0) ? bl0 : (li == 1) ? bl1 : bl2;
        const float* bs = (li == 0) ? bs0 : (li == 1) ? bs1 : bs2;
        bias[i] = bl[j] + bs[j];
    }
}

// ---------------------------------------------------------------------------
// x (f32) -> xb (bf16), 8 elems/thread
// ---------------------------------------------------------------------------
__global__ __launch_bounds__(256) void conv_kernel(const float* __restrict__ in,
                                                   unsigned short* __restrict__ outb,
                                                   int nElem) {
    int base = (blockIdx.x * blockDim.x + threadIdx.x) * 8;
    if (base >= nElem) return;
    float4 a = *(const float4*)(in + base);
    float4 b = *(const float4*)(in + base + 4);
    ushort4 p0 = {f2bf(a.x), f2bf(a.y), f2bf(a.z), f2bf(a.w)};
    ushort4 p1 = {f2bf(b.x), f2bf(b.y), f2bf(b.z), f2bf(b.w)};
    *(ushort4*)(outb + base) = p0;
    *(ushort4*)(outb + base + 4) = p1;
}

// ---------------------------------------------------------------------------
// Fused layer: phase 1 max-aggregates 64 nodes into LDS (XOR-swizzled 16B
// chunks, identical on write and read). Phase 2: MFMA transform; agg B-frag
// from LDS, h B-frag + weights from global.
// ---------------------------------------------------------------------------
template <bool BF16OUT>
__global__ __launch_bounds__(256) void fused_layer_kernel(
        const unsigned short* __restrict__ hb,
        const int* __restrict__ off,
        const int* __restrict__ csr_src,
        const unsigned short* __restrict__ Wlb,
        const unsigned short* __restrict__ Wcb,
        const float* __restrict__ bias,
        float* __restrict__ outf,
        unsigned short* __restrict__ outb,
        int nNodes) {
    __shared__ __align__(16) unsigned short agg_s[64 * FEAT];   // 8 KB

    int t = threadIdx.x;
    int nb0 = blockIdx.x * 64;

    // ---- phase 1: gather-max 64 nodes (32 groups x 8 lanes, 2 nodes each) --
    int g = t >> 3;
    int q = t & 7;
#pragma unroll
    for (int rep = 0; rep < 2; ++rep) {
        int nl = rep * 32 + g;
        int n = nb0 + nl;
        uint4 outv = make_uint4(0, 0, 0, 0);
        if (n < nNodes) {
            int e0 = off[n], e1 = off[n + 1];
            if (e1 > e0) {
                const float NEG = -INFINITY;
                float acc[8] = {NEG, NEG, NEG, NEG, NEG, NEG, NEG, NEG};
#define ACCUM(v)                                                            \
                acc[0] = fmaxf(acc[0], bf_lo(v.x)); acc[1] = fmaxf(acc[1], bf_hi(v.x)); \
                acc[2] = fmaxf(acc[2], bf_lo(v.y)); acc[3] = fmaxf(acc[3], bf_hi(v.y)); \
                acc[4] = fmaxf(acc[4], bf_lo(v.z)); acc[5] = fmaxf(acc[5], bf_hi(v.z)); \
                acc[6] = fmaxf(acc[6], bf_lo(v.w)); acc[7] = fmaxf(acc[7], bf_hi(v.w));
                int e = e0;
                for (; e + 4 <= e1; e += 4) {
                    int s0 = csr_src[e],     s1 = csr_src[e + 1];
                    int s2 = csr_src[e + 2], s3 = csr_src[e + 3];
                    uint4 v0 = *(const uint4*)&hb[(size_t)s0 * FEAT + q * 8];
                    uint4 v1 = *(const uint4*)&hb[(size_t)s1 * FEAT + q * 8];
                    uint4 v2 = *(const uint4*)&hb[(size_t)s2 * FEAT + q * 8];
                    uint4 v3 = *(const uint4*)&hb[(size_t)s3 * FEAT + q * 8];
                    ACCUM(v0) ACCUM(v1) ACCUM(v2) ACCUM(v3)
                }
                for (; e < e1; ++e) {
                    int s0 = csr_src[e];
                    uint4 v0 = *(const uint4*)&hb[(size_t)s0 * FEAT + q * 8];
                    ACCUM(v0)
                }
#undef ACCUM
                outv.x = pack_exact(acc[0], acc[1]);
                outv.y = pack_exact(acc[2], acc[3]);
                outv.z = pack_exact(acc[4], acc[5]);
                outv.w = pack_exact(acc[6], acc[7]);
            }
        }
        *(uint4*)&agg_s[nl * FEAT + ((q ^ (nl & 7)) << 3)] = outv;   // swizzled
    }
    __syncthreads();

    // ---- phase 2: MFMA transform (wave = f-quarter, 4 tiles of 16 nodes) --
    int wave = t >> 6, lane = t & 63;
    int f0 = wave << 4, lm = lane & 15, lk = lane >> 4;

    short8 aWl0 = *(const short8*)&Wlb[(f0 + lm) * FEAT + lk * 8];
    short8 aWl1 = *(const short8*)&Wlb[(f0 + lm) * FEAT + lk * 8 + 32];
    short8 aWc0 = *(const short8*)&Wcb[(f0 + lm) * FEAT + lk * 8];
    short8 aWc1 = *(const short8*)&Wcb[(f0 + lm) * FEAT + lk * 8 + 32];
    f32x4 b4 = *(const f32x4*)&bias[f0 + lk * 4];

#pragma unroll
    for (int tile = 0; tile < 4; ++tile) {
        int nl = tile * 16 + lm;
        int n = nb0 + nl;
        int nr = (n < nNodes) ? n : (nNodes - 1);
        const unsigned short* __restrict__ hr = hb + (size_t)nr * FEAT;
        short8 bA0 = *(const short8*)&agg_s[nl * FEAT + (((lk)     ^ (nl & 7)) << 3)];
        short8 bA1 = *(const short8*)&agg_s[nl * FEAT + (((lk + 4) ^ (nl & 7)) << 3)];
        short8 bH0 = *(const short8*)(hr + lk * 8);
        short8 bH1 = *(const short8*)(hr + lk * 8 + 32);

        f32x4 acc = {0.f, 0.f, 0.f, 0.f};
        acc = __builtin_amdgcn_mfma_f32_16x16x32_bf16(aWl0, bA0, acc, 0, 0, 0);
        acc = __builtin_amdgcn_mfma_f32_16x16x32_bf16(aWl1, bA1, acc, 0, 0, 0);
        acc = __builtin_amdgcn_mfma_f32_16x16x32_bf16(aWc0, bH0, acc, 0, 0, 0);
        acc = __builtin_amdgcn_mfma_f32_16x16x32_bf16(aWc1, bH1, acc, 0, 0, 0);

        if (n < nNodes) {
            float v0 = fmaxf(acc[0] + b4[0], 0.f);
            float v1 = fmaxf(acc[1] + b4[1], 0.f);
            float v2 = fmaxf(acc[2] + b4[2], 0.f);
            float v3 = fmaxf(acc[3] + b4[3], 0.f);
            if (BF16OUT) {
                ushort4 p = {f2bf(v0), f2bf(v1), f2bf(v2), f2bf(v3)};
                *(ushort4*)&outb[(size_t)n * FEAT + f0 + lk * 4] = p;
            } else {
                float4 p = make_float4(v0, v1, v2, v3);
                *(float4*)&outf[(size_t)n * FEAT + f0 + lk * 4] = p;
            }
        }
    }
}

// ---------------------------------------------------------------------------
extern "C" void kernel_launch(void* const* d_in, const int* in_sizes, int n_in,
                              void* d_out, int out_size, void* d_ws, size_t ws_size,
                              hipStream_t stream) {
    const float* x   = (const float*)d_in[0];
    const int* eidx  = (const int*)d_in[1];
    const int N  = in_sizes[0] / FEAT;
    const int E  = in_sizes[1] / 2;
    const int* src = eidx;
    const int* dst = eidx + E;

    const float* Wl[3]; const float* bl[3]; const float* Wr[3];
    const float* Ws[3]; const float* bs[3];
    for (int li = 0; li < 3; ++li) {
        Wl[li] = (const float*)d_in[2 + 5 * li + 0];
        bl[li] = (const float*)d_in[2 + 5 * li + 1];
        Wr[li] = (const float*)d_in[2 + 5 * li + 2];
        Ws[li] = (const float*)d_in[2 + 5 * li + 3];
        bs[li] = (const float*)d_in[2 + 5 * li + 4];
    }

    auto align256 = [](size_t v) { return (v + 255) & ~(size_t)255; };
    char* ws = (char*)d_ws;
    int* off       = (int*)ws;  ws += align256((size_t)(N + 1) * 4);
    int* bktCnt    = (int*)ws;  ws += align256(NB_PAD * 4);
    int* baseC     = (int*)ws;  ws += align256((NB_PAD + 1) * 4);
    int* baseP     = (int*)ws;  ws += align256((NB_PAD + 1) * 4);
    int* bktCursor = (int*)ws;  ws += align256(NB_PAD * 4);
    unsigned* pairs = (unsigned*)ws; ws += align256(((size_t)E + 16 * NB_PAD + 64) * 4);
    int* csr_src   = (int*)ws;  ws += align256((size_t)E * 4);
    unsigned short* wlb = (unsigned short*)ws; ws += align256(3 * FEAT * FEAT * 2);
    unsigned short* wcb = (unsigned short*)ws; ws += align256(3 * FEAT * FEAT * 2);
    float* biasbuf = (float*)ws; ws += align256(3 * FEAT * 4);
    unsigned short* xb  = (unsigned short*)ws; ws += align256((size_t)N * FEAT * 2);
    unsigned short* h1b = (unsigned short*)ws; ws += align256((size_t)N * FEAT * 2);
    unsigned short* h2b = (unsigned short*)ws; ws += align256((size_t)N * FEAT * 2);

    const int TB = 256;
    int nBkt = (N + (1 << BKT_SHIFT) - 1) >> BKT_SHIFT;   // 196

    // ---- CSR build: hist -> scan -> partition -> per-bucket finalize ----
    hipMemsetAsync(bktCnt, 0, NB_PAD * 4, stream);
    hist_kernel<<<PART_GRID, PART_TB, 0, stream>>>(dst, bktCnt, E);
    bucket_scan_kernel<<<1, TB, 0, stream>>>(bktCnt, baseC, baseP, bktCursor);
    partition_kernel<<<PART_GRID, PART_TB, 0, stream>>>(src, dst, bktCursor, pairs, E);
    csr_bucket_kernel<<<nBkt, 512, 0, stream>>>(pairs, baseP, baseC, bktCnt, off, csr_src, N, E);

    prep_kernel<<<(3 * FEAT * FEAT + TB - 1) / TB, TB, 0, stream>>>(
        Wl[0], Wr[0], Ws[0], bl[0], bs[0],
        Wl[1], Wr[1], Ws[1], bl[1], bs[1],
        Wl[2], Wr[2], Ws[2], bl[2], bs[2], wlb, wcb, biasbuf);
    int convBlocks = (N * FEAT / 8 + TB - 1) / TB;
    conv_kernel<<<convBlocks, TB, 0, stream>>>(x, xb, N * FEAT);

    int fusedBlocks = (N + 63) / 64;

    // ---- layer 0 ----
    fused_layer_kernel<true><<<fusedBlocks, TB, 0, stream>>>(
        xb, off, csr_src, wlb + 0 * 4096, wcb + 0 * 4096, biasbuf + 0 * 64,
        nullptr, h1b, N);
    // ---- layer 1 ----
    fused_layer_kernel<true><<<fusedBlocks, TB, 0, stream>>>(
        h1b, off, csr_src, wlb + 1 * 4096, wcb + 1 * 4096, biasbuf + 1 * 64,
        nullptr, h2b, N);
    // ---- layer 2 (f32 output) ----
    fused_layer_kernel<false><<<fusedBlocks, TB, 0, stream>>>(
        h2b, off, csr_src, wlb + 2 * 4096, wcb + 2 * 4096, biasbuf + 2 * 64,
        (float*)d_out, nullptr, N);
}